// Round 1
// baseline (457.413 us; speedup 1.0000x reference)
//
#include <hip/hip_runtime.h>
#include <math.h>

typedef float f32x4 __attribute__((ext_vector_type(4)));
typedef short s16x8 __attribute__((ext_vector_type(8)));

#define DIM_ 768
#define HEADS_ 12
#define DH_ 64
#define HID_ 3072
#define SEQ_ 1024
#define BATCH_ 8
#define ROWS_ (BATCH_*SEQ_)   // 8192

static __device__ __forceinline__ ushort f2bf(float f) {
    union { float f; unsigned u; } v; v.f = f;
    unsigned r = (v.u + 0x7fffu + ((v.u >> 16) & 1u)) >> 16;
    return (ushort)r;
}

// ---------------- prep: cast x to bf16 ----------------
__global__ __launch_bounds__(256) void cast_bf16_kernel(
    const float* __restrict__ in, ushort* __restrict__ out, int n4)
{
    int i = blockIdx.x * 256 + threadIdx.x;
    if (i >= n4) return;
    float4 v = ((const float4*)in)[i];
    ushort4 o;
    o.x = f2bf(v.x); o.y = f2bf(v.y); o.z = f2bf(v.z); o.w = f2bf(v.w);
    ((ushort4*)out)[i] = o;
}

// ---------------- prep: transpose+cast W[K][N] -> WT[N][K] bf16 ----------------
__global__ __launch_bounds__(256) void transpose_cast_kernel(
    const float* __restrict__ W, ushort* __restrict__ WT, int K, int N)
{
    __shared__ float tile[32][33];
    int n0 = blockIdx.x * 32, k0 = blockIdx.y * 32;
    int tx = threadIdx.x, ty = threadIdx.y; // 32 x 8
#pragma unroll
    for (int i = 0; i < 4; i++)
        tile[ty + i * 8][tx] = W[(size_t)(k0 + ty + i * 8) * N + n0 + tx];
    __syncthreads();
#pragma unroll
    for (int i = 0; i < 4; i++)
        WT[(size_t)(n0 + ty + i * 8) * K + k0 + tx] = f2bf(tile[tx][ty + i * 8]);
}

// ---------------- GEMM: C[M][N] = A[M][K](bf16) @ BT[N][K](bf16)^T + bias ----------------
#define EPI_F32 0
#define EPI_GELU 1
#define EPI_QKV 2

template<int EPI>
__global__ __launch_bounds__(256, 2) void gemm_bt(
    const ushort* __restrict__ A, const ushort* __restrict__ B,
    const float* __restrict__ bias,
    float* __restrict__ Cf, ushort* __restrict__ Cbf,
    ushort* __restrict__ Qb, ushort* __restrict__ Kb, ushort* __restrict__ Vt,
    int M, int N, int K)
{
    __shared__ ushort As[128 * 32];
    __shared__ ushort Bs[128 * 32];
    const int t = threadIdx.x;
    const int lane = t & 63;
    const int w = t >> 6;
    const int wr = w >> 1, wc = w & 1;
    const int m0 = blockIdx.y * 128, n0 = blockIdx.x * 128;
    const int lr = lane & 15, lk = (lane >> 4) * 8;

    f32x4 acc[4][4] = {};
    const int arow0 = m0 + (t >> 2);
    const int brow0 = n0 + (t >> 2);
    const int cof = (t & 3) * 8;

    for (int k0 = 0; k0 < K; k0 += 32) {
        s16x8 a0 = *(const s16x8*)(A + (size_t)arow0 * K + k0 + cof);
        s16x8 a1 = *(const s16x8*)(A + (size_t)(arow0 + 64) * K + k0 + cof);
        s16x8 b0 = *(const s16x8*)(B + (size_t)brow0 * K + k0 + cof);
        s16x8 b1 = *(const s16x8*)(B + (size_t)(brow0 + 64) * K + k0 + cof);
        __syncthreads();
        *(s16x8*)&As[t * 8] = a0;
        *(s16x8*)&As[(t + 256) * 8] = a1;
        *(s16x8*)&Bs[t * 8] = b0;
        *(s16x8*)&Bs[(t + 256) * 8] = b1;
        __syncthreads();
        s16x8 af[4], bfr[4];
#pragma unroll
        for (int m = 0; m < 4; m++)
            af[m] = *(const s16x8*)&As[(wr * 64 + m * 16 + lr) * 32 + lk];
#pragma unroll
        for (int n = 0; n < 4; n++)
            bfr[n] = *(const s16x8*)&Bs[(wc * 64 + n * 16 + lr) * 32 + lk];
#pragma unroll
        for (int m = 0; m < 4; m++)
#pragma unroll
            for (int n = 0; n < 4; n++)
                acc[m][n] = __builtin_amdgcn_mfma_f32_16x16x32_bf16(af[m], bfr[n], acc[m][n], 0, 0, 0);
    }

#pragma unroll
    for (int m = 0; m < 4; m++) {
        int row = m0 + wr * 64 + m * 16 + (lane >> 4) * 4;
#pragma unroll
        for (int n = 0; n < 4; n++) {
            int col = n0 + wc * 64 + n * 16 + lr;
            float bv = bias[col];
#pragma unroll
            for (int r = 0; r < 4; r++) {
                float v = acc[m][n][r] + bv;
                int rg = row + r;
                if (EPI == EPI_F32) {
                    Cf[(size_t)rg * N + col] = v;
                } else if (EPI == EPI_GELU) {
                    float gl = 0.5f * v * (1.0f + erff(v * 0.70710678118654752f));
                    Cbf[(size_t)rg * N + col] = f2bf(gl);
                } else { // QKV scatter: col = h*192 + dh*3 + which
                    int b = rg >> 10, nrow = rg & 1023;
                    int h = col / 192, rem = col % 192;
                    int dh = rem / 3, wh = rem % 3;
                    int hb = b * HEADS_ + h;
                    ushort bw = f2bf(v);
                    if (wh == 0)      Qb[((size_t)hb * SEQ_ + nrow) * DH_ + dh] = bw;
                    else if (wh == 1) Kb[((size_t)hb * SEQ_ + nrow) * DH_ + dh] = bw;
                    else              Vt[(size_t)hb * DH_ * SEQ_ + (size_t)dh * SEQ_ + nrow] = bw;
                }
            }
        }
    }
}

// ---------------- flash-style attention ----------------
// Q,K: [b*h][1024][64] bf16 ; Vt: [b*h][64][1024] bf16 ; AO: [8192][768] bf16
__global__ __launch_bounds__(256, 2) void attn_kernel(
    const ushort* __restrict__ Q, const ushort* __restrict__ Kb,
    const ushort* __restrict__ Vt, ushort* __restrict__ AO)
{
    __shared__ ushort Pl[4][16 * 64];
    const int t = threadIdx.x, lane = t & 63, w = t >> 6;
    const int lr = lane & 15, lk4 = lane >> 4;
    const int qt = blockIdx.x;   // 0..15
    const int bh = blockIdx.y;   // 0..95
    const int b = bh / HEADS_, h = bh % HEADS_;
    const ushort* qh = Q + (size_t)bh * SEQ_ * DH_;
    const ushort* kh = Kb + (size_t)bh * SEQ_ * DH_;
    const ushort* vh = Vt + (size_t)bh * DH_ * SEQ_;

    int qrow = qt * 64 + w * 16 + lr;
    s16x8 aq0 = *(const s16x8*)(qh + (size_t)qrow * DH_ + lk4 * 8);
    s16x8 aq1 = *(const s16x8*)(qh + (size_t)qrow * DH_ + 32 + lk4 * 8);

    float mrow[4], lrow[4];
    f32x4 O[4] = {};
#pragma unroll
    for (int r = 0; r < 4; r++) { mrow[r] = -INFINITY; lrow[r] = 0.f; }

    for (int tkv = 0; tkv < 16; ++tkv) {
        int kbase = tkv * 64;
        f32x4 S[4] = {};
#pragma unroll
        for (int n = 0; n < 4; n++) {
            int kid = kbase + n * 16 + lr;
            s16x8 bk0 = *(const s16x8*)(kh + (size_t)kid * DH_ + lk4 * 8);
            s16x8 bk1 = *(const s16x8*)(kh + (size_t)kid * DH_ + 32 + lk4 * 8);
            S[n] = __builtin_amdgcn_mfma_f32_16x16x32_bf16(aq0, bk0, S[n], 0, 0, 0);
            S[n] = __builtin_amdgcn_mfma_f32_16x16x32_bf16(aq1, bk1, S[n], 0, 0, 0);
        }
        float scale[4];
#pragma unroll
        for (int r = 0; r < 4; r++) {
            float v = fmaxf(fmaxf(S[0][r], S[1][r]), fmaxf(S[2][r], S[3][r]));
            v = fmaxf(v, __shfl_xor(v, 1)); v = fmaxf(v, __shfl_xor(v, 2));
            v = fmaxf(v, __shfl_xor(v, 4)); v = fmaxf(v, __shfl_xor(v, 8));
            float mn = fmaxf(mrow[r], v);
            scale[r] = __expf(mrow[r] - mn);
            mrow[r] = mn;
        }
#pragma unroll
        for (int n = 0; n < 4; n++) {
#pragma unroll
            for (int r = 0; r < 4; r++) {
                float p = __expf(S[n][r] - mrow[r]);
                S[n][r] = p;
                Pl[w][(lk4 * 4 + r) * 64 + n * 16 + lr] = f2bf(p);
            }
        }
#pragma unroll
        for (int r = 0; r < 4; r++) {
            float s = S[0][r] + S[1][r] + S[2][r] + S[3][r];
            s += __shfl_xor(s, 1); s += __shfl_xor(s, 2);
            s += __shfl_xor(s, 4); s += __shfl_xor(s, 8);
            lrow[r] = lrow[r] * scale[r] + s;
        }
#pragma unroll
        for (int n = 0; n < 4; n++)
#pragma unroll
            for (int r = 0; r < 4; r++) O[n][r] *= scale[r];

        s16x8 ap0 = *(const s16x8*)&Pl[w][lr * 64 + lk4 * 8];
        s16x8 ap1 = *(const s16x8*)&Pl[w][lr * 64 + 32 + lk4 * 8];
#pragma unroll
        for (int n = 0; n < 4; n++) {
            s16x8 bv0 = *(const s16x8*)(vh + (size_t)(n * 16 + lr) * SEQ_ + kbase + lk4 * 8);
            s16x8 bv1 = *(const s16x8*)(vh + (size_t)(n * 16 + lr) * SEQ_ + kbase + 32 + lk4 * 8);
            O[n] = __builtin_amdgcn_mfma_f32_16x16x32_bf16(ap0, bv0, O[n], 0, 0, 0);
            O[n] = __builtin_amdgcn_mfma_f32_16x16x32_bf16(ap1, bv1, O[n], 0, 0, 0);
        }
    }
    const float fin = 0.03608439182435161f; // 1/sqrt(768), applied post-softmax
#pragma unroll
    for (int r = 0; r < 4; r++) {
        float s = fin / lrow[r];
        int rg = b * SEQ_ + qt * 64 + w * 16 + lk4 * 4 + r;
#pragma unroll
        for (int n = 0; n < 4; n++)
            AO[(size_t)rg * DIM_ + h * DH_ + n * 16 + lr] = f2bf(O[n][r] * s);
    }
}

// ---------------- fused residual + LayerNorm (wave per row) ----------------
__global__ __launch_bounds__(256) void ln_residual_kernel(
    const float* __restrict__ xin, const float* __restrict__ y,
    const float* __restrict__ g, const float* __restrict__ be,
    float* __restrict__ outf, ushort* __restrict__ outbf, int rows)
{
    int w = threadIdx.x >> 6, lane = threadIdx.x & 63;
    int row = blockIdx.x * 4 + w;
    if (row >= rows) return;
    const float* yr = y + (size_t)row * DIM_;
    float v[12];
    float s = 0.f, s2 = 0.f;
#pragma unroll
    for (int i = 0; i < 12; i++) {
        v[i] = yr[i * 64 + lane];
        s += v[i]; s2 += v[i] * v[i];
    }
#pragma unroll
    for (int o = 1; o < 64; o <<= 1) { s += __shfl_xor(s, o); s2 += __shfl_xor(s2, o); }
    float mu = s * (1.f / 768.f);
    float var = s2 * (1.f / 768.f) - mu * mu;
    float rs = rsqrtf(var + 1e-5f);
    const float* xr = xin + (size_t)row * DIM_;
#pragma unroll
    for (int i = 0; i < 12; i++) {
        int c = i * 64 + lane;
        float o = xr[c] + (v[i] - mu) * rs * g[c] + be[c];
        outf[(size_t)row * DIM_ + c] = o;
        if (outbf) outbf[(size_t)row * DIM_ + c] = f2bf(o);
    }
}

// ---------------- launch ----------------
extern "C" void kernel_launch(void* const* d_in, const int* in_sizes, int n_in,
                              void* d_out, int out_size, void* d_ws, size_t ws_size,
                              hipStream_t stream)
{
    const float* x    = (const float*)d_in[0];
    const float* Wqkv = (const float*)d_in[1];
    const float* bqkv = (const float*)d_in[2];
    const float* Wproj= (const float*)d_in[3];
    const float* bproj= (const float*)d_in[4];
    const float* W1   = (const float*)d_in[5];
    const float* b1   = (const float*)d_in[6];
    const float* W2   = (const float*)d_in[7];
    const float* b2   = (const float*)d_in[8];
    const float* g1   = (const float*)d_in[9];
    const float* be1  = (const float*)d_in[10];
    const float* g2   = (const float*)d_in[11];
    const float* be2  = (const float*)d_in[12];
    float* out = (float*)d_out;

    char* ws = (char*)d_ws;
    size_t off = 0;
    auto alloc = [&](size_t bytes) -> void* {
        void* p = ws + off;
        off += (bytes + 255) & ~(size_t)255;
        return p;
    };
    ushort* xbf    = (ushort*)alloc((size_t)ROWS_ * DIM_ * 2);
    ushort* wqkvT  = (ushort*)alloc((size_t)2304 * 768 * 2);
    ushort* wprojT = (ushort*)alloc((size_t)768 * 768 * 2);
    ushort* w1T    = (ushort*)alloc((size_t)3072 * 768 * 2);
    ushort* w2T    = (ushort*)alloc((size_t)768 * 3072 * 2);
    ushort* qb     = (ushort*)alloc((size_t)ROWS_ * DIM_ * 2);
    ushort* kb     = (ushort*)alloc((size_t)ROWS_ * DIM_ * 2);
    ushort* vT     = (ushort*)alloc((size_t)ROWS_ * DIM_ * 2);
    ushort* aobf   = (ushort*)alloc((size_t)ROWS_ * DIM_ * 2);
    float*  projf  = (float*) alloc((size_t)ROWS_ * DIM_ * 4);  // reused for mlp_out
    float*  x1f    = (float*) alloc((size_t)ROWS_ * DIM_ * 4);
    ushort* x1bf   = (ushort*)alloc((size_t)ROWS_ * DIM_ * 2);
    ushort* hbf    = (ushort*)alloc((size_t)ROWS_ * HID_ * 2);

    // prep
    cast_bf16_kernel<<<(ROWS_ * DIM_ / 4 + 255) / 256, 256, 0, stream>>>(x, xbf, ROWS_ * DIM_ / 4);
    transpose_cast_kernel<<<dim3(2304 / 32, 768 / 32), dim3(32, 8), 0, stream>>>(Wqkv, wqkvT, 768, 2304);
    transpose_cast_kernel<<<dim3(768 / 32, 768 / 32), dim3(32, 8), 0, stream>>>(Wproj, wprojT, 768, 768);
    transpose_cast_kernel<<<dim3(3072 / 32, 768 / 32), dim3(32, 8), 0, stream>>>(W1, w1T, 768, 3072);
    transpose_cast_kernel<<<dim3(768 / 32, 3072 / 32), dim3(32, 8), 0, stream>>>(W2, w2T, 3072, 768);

    // qkv = x @ Wqkv + bqkv  -> scatter into q/k/vT
    gemm_bt<EPI_QKV><<<dim3(2304 / 128, ROWS_ / 128), 256, 0, stream>>>(
        xbf, wqkvT, bqkv, nullptr, nullptr, qb, kb, vT, ROWS_, 2304, 768);

    // attention -> aobf [8192][768]
    attn_kernel<<<dim3(SEQ_ / 64, BATCH_ * HEADS_), 256, 0, stream>>>(qb, kb, vT, aobf);

    // proj
    gemm_bt<EPI_F32><<<dim3(768 / 128, ROWS_ / 128), 256, 0, stream>>>(
        aobf, wprojT, bproj, projf, nullptr, nullptr, nullptr, nullptr, ROWS_, 768, 768);

    // x1 = x + LN(proj)
    ln_residual_kernel<<<ROWS_ / 4, 256, 0, stream>>>(x, projf, g1, be1, x1f, x1bf, ROWS_);

    // h = gelu(x1 @ W1 + b1)
    gemm_bt<EPI_GELU><<<dim3(3072 / 128, ROWS_ / 128), 256, 0, stream>>>(
        x1bf, w1T, b1, nullptr, hbf, nullptr, nullptr, nullptr, ROWS_, 3072, 768);

    // mlp = h @ W2 + b2 (reuse projf)
    gemm_bt<EPI_F32><<<dim3(768 / 128, ROWS_ / 128), 256, 0, stream>>>(
        hbf, w2T, b2, projf, nullptr, nullptr, nullptr, nullptr, ROWS_, 768, 3072);

    // out = x1 + LN(mlp)
    ln_residual_kernel<<<ROWS_ / 4, 256, 0, stream>>>(x1f, projf, g2, be2, out, nullptr, ROWS_);
}

// Round 3
// 449.518 us; speedup vs baseline: 1.0176x; 1.0176x over previous
//
#include <hip/hip_runtime.h>
#include <math.h>

typedef float f32x4 __attribute__((ext_vector_type(4)));
typedef short s16x8 __attribute__((ext_vector_type(8)));

#define DIM_ 768
#define HEADS_ 12
#define DH_ 64
#define HID_ 3072
#define SEQ_ 1024
#define BATCH_ 8
#define ROWS_ (BATCH_*SEQ_)   // 8192

static __device__ __forceinline__ ushort f2bf(float f) {
    union { float f; unsigned u; } v; v.f = f;
    unsigned r = (v.u + 0x7fffu + ((v.u >> 16) & 1u)) >> 16;
    return (ushort)r;
}

static __device__ __forceinline__ void glds16(const ushort* gp, ushort* lp) {
    __builtin_amdgcn_global_load_lds(
        (const __attribute__((address_space(1))) void*)gp,
        (__attribute__((address_space(3))) void*)lp, 16, 0, 0);
}

// ---------------- prep: cast x to bf16 ----------------
__global__ __launch_bounds__(256) void cast_bf16_kernel(
    const float* __restrict__ in, ushort* __restrict__ out, int n4)
{
    int i = blockIdx.x * 256 + threadIdx.x;
    if (i >= n4) return;
    float4 v = ((const float4*)in)[i];
    ushort4 o;
    o.x = f2bf(v.x); o.y = f2bf(v.y); o.z = f2bf(v.z); o.w = f2bf(v.w);
    ((ushort4*)out)[i] = o;
}

// ---------------- prep: transpose+cast W[K][N] -> WT[N][K] bf16 ----------------
__global__ __launch_bounds__(256) void transpose_cast_kernel(
    const float* __restrict__ W, ushort* __restrict__ WT, int K, int N)
{
    __shared__ float tile[32][33];
    int n0 = blockIdx.x * 32, k0 = blockIdx.y * 32;
    int tx = threadIdx.x, ty = threadIdx.y; // 32 x 8
#pragma unroll
    for (int i = 0; i < 4; i++)
        tile[ty + i * 8][tx] = W[(size_t)(k0 + ty + i * 8) * N + n0 + tx];
    __syncthreads();
#pragma unroll
    for (int i = 0; i < 4; i++)
        WT[(size_t)(n0 + ty + i * 8) * K + k0 + tx] = f2bf(tile[tx][ty + i * 8]);
}

// ---------------- GEMM: C[M][N] = A[M][K](bf16) @ BT[N][K](bf16)^T + bias ----------------
#define EPI_F32 0
#define EPI_GELU 1
#define EPI_QKV 2

template<int EPI>
__global__ __launch_bounds__(256, 2) void gemm_bt(
    const ushort* __restrict__ A, const ushort* __restrict__ B,
    const float* __restrict__ bias,
    float* __restrict__ Cf, ushort* __restrict__ Cbf,
    ushort* __restrict__ Qb, ushort* __restrict__ Kb, ushort* __restrict__ Vt,
    int M, int N, int K)
{
    __shared__ ushort As[128 * 32];
    __shared__ ushort Bs[128 * 32];
    const int t = threadIdx.x;
    const int lane = t & 63;
    const int w = t >> 6;
    const int wr = w >> 1, wc = w & 1;
    const int m0 = blockIdx.y * 128, n0 = blockIdx.x * 128;
    const int lr = lane & 15, lk = (lane >> 4) * 8;

    // global_load_lds staging: wave w stages chunks {w, w+4} of A and B.
    // LDS dest is wave-uniform base; HW writes base + lane*16B -> row=lane/4, col8=lane%4 (linear).
    const int srow = lane >> 2, scol = (lane & 3) * 8;
    const ushort* Ag0 = A + (size_t)(m0 + w * 16 + srow) * K + scol;
    const ushort* Ag1 = A + (size_t)(m0 + 64 + w * 16 + srow) * K + scol;
    const ushort* Bg0 = B + (size_t)(n0 + w * 16 + srow) * K + scol;
    const ushort* Bg1 = B + (size_t)(n0 + 64 + w * 16 + srow) * K + scol;
    ushort* as0 = &As[(w * 16) * 32];
    ushort* as1 = &As[(64 + w * 16) * 32];
    ushort* bs0 = &Bs[(w * 16) * 32];
    ushort* bs1 = &Bs[(64 + w * 16) * 32];

    f32x4 acc[4][4] = {};

    for (int k0 = 0; k0 < K; k0 += 32) {
        glds16(Ag0 + k0, as0);
        glds16(Ag1 + k0, as1);
        glds16(Bg0 + k0, bs0);
        glds16(Bg1 + k0, bs1);
        __syncthreads();   // drains vmcnt(0): staged tile visible to all waves
        s16x8 af[4], bfr[4];
#pragma unroll
        for (int m = 0; m < 4; m++)
            af[m] = *(const s16x8*)&As[(wr * 64 + m * 16 + lr) * 32 + lk];
#pragma unroll
        for (int n = 0; n < 4; n++)
            bfr[n] = *(const s16x8*)&Bs[(wc * 64 + n * 16 + lr) * 32 + lk];
#pragma unroll
        for (int m = 0; m < 4; m++)
#pragma unroll
            for (int n = 0; n < 4; n++)
                acc[m][n] = __builtin_amdgcn_mfma_f32_16x16x32_bf16(af[m], bfr[n], acc[m][n], 0, 0, 0);
        __syncthreads();   // compute done before next iter's staging overwrites
    }

#pragma unroll
    for (int m = 0; m < 4; m++) {
        int row = m0 + wr * 64 + m * 16 + (lane >> 4) * 4;
#pragma unroll
        for (int n = 0; n < 4; n++) {
            int col = n0 + wc * 64 + n * 16 + lr;
            float bv = bias[col];
#pragma unroll
            for (int r = 0; r < 4; r++) {
                float v = acc[m][n][r] + bv;
                int rg = row + r;
                if (EPI == EPI_F32) {
                    Cf[(size_t)rg * N + col] = v;
                } else if (EPI == EPI_GELU) {
                    float gl = 0.5f * v * (1.0f + erff(v * 0.70710678118654752f));
                    Cbf[(size_t)rg * N + col] = f2bf(gl);
                } else { // QKV scatter: col = h*192 + dh*3 + which
                    int b = rg >> 10, nrow = rg & 1023;
                    int h = col / 192, rem = col % 192;
                    int dh = rem / 3, wh = rem % 3;
                    int hb = b * HEADS_ + h;
                    ushort bw = f2bf(v);
                    if (wh == 0)      Qb[((size_t)hb * SEQ_ + nrow) * DH_ + dh] = bw;
                    else if (wh == 1) Kb[((size_t)hb * SEQ_ + nrow) * DH_ + dh] = bw;
                    else              Vt[(size_t)hb * DH_ * SEQ_ + (size_t)dh * SEQ_ + nrow] = bw;
                }
            }
        }
    }
}

// ---------------- flash attention, swapped QK^T, zero-LDS ----------------
// Q,K: [b*h][1024][64] bf16 ; Vt: [b*h][64][1024] bf16 ; AO: [8192][768] bf16
// Per wave: 16 q rows. S^T = mfma(K,Q): lane(g=lane>>4, q=lane&15) holds
// P[q][kbase + 16n + 4g + r] in S[n][r]. Softmax reduces: in-lane + shfl_xor 16/32.
// P -> PV A-frag: per packed pair, permlane32_swap + permlane16_swap produce the
// two fragment words (src group g' = 2(g&1)+h).
__global__ __launch_bounds__(256) void attn_kernel(
    const ushort* __restrict__ Q, const ushort* __restrict__ Kb,
    const ushort* __restrict__ Vt, ushort* __restrict__ AO)
{
    const int t = threadIdx.x, lane = t & 63, w = t >> 6;
    const int lr = lane & 15, g = lane >> 4;
    const int qt = blockIdx.x;   // 0..15
    const int bh = blockIdx.y;   // 0..95
    const int b = bh / HEADS_, h = bh % HEADS_;
    const ushort* qh = Q + (size_t)bh * SEQ_ * DH_;
    const ushort* kh = Kb + (size_t)bh * SEQ_ * DH_;
    const ushort* vh = Vt + (size_t)bh * DH_ * SEQ_;

    // Q fragment (B operand): col=lr=q_local, k-elem dh = g*8+j
    const int qrow = qt * 64 + w * 16 + lr;
    s16x8 aq0 = *(const s16x8*)(qh + (size_t)qrow * DH_ + g * 8);
    s16x8 aq1 = *(const s16x8*)(qh + (size_t)qrow * DH_ + 32 + g * 8);

    float mrow = -INFINITY, lrow = 0.f;
    f32x4 O[4] = {};   // O[n_dh][r] = O[q=4g+r][dh=16*n_dh+lr]

    for (int tkv = 0; tkv < 16; ++tkv) {
        const int kbase = tkv * 64;
        f32x4 S[4] = {};
#pragma unroll
        for (int n = 0; n < 4; n++) {
            const ushort* kp = kh + (size_t)(kbase + n * 16 + lr) * DH_ + g * 8;
            s16x8 k0 = *(const s16x8*)kp;
            s16x8 k1 = *(const s16x8*)(kp + 32);
            S[n] = __builtin_amdgcn_mfma_f32_16x16x32_bf16(k0, aq0, S[n], 0, 0, 0);
            S[n] = __builtin_amdgcn_mfma_f32_16x16x32_bf16(k1, aq1, S[n], 0, 0, 0);
        }
        // row max over this tile (q = lr): in-lane tree + 2 shfls
        f32x4 mm = S[0];
#pragma unroll
        for (int n = 1; n < 4; n++) {
#pragma unroll
            for (int r = 0; r < 4; r++) mm[r] = fmaxf(mm[r], S[n][r]);
        }
        float mx = fmaxf(fmaxf(mm[0], mm[1]), fmaxf(mm[2], mm[3]));
        mx = fmaxf(mx, __shfl_xor(mx, 16));
        mx = fmaxf(mx, __shfl_xor(mx, 32));
        float mn = fmaxf(mrow, mx);
        float scale = __expf(mrow - mn);
        mrow = mn;
        // exponentiate + row sum
#pragma unroll
        for (int n = 0; n < 4; n++)
#pragma unroll
            for (int r = 0; r < 4; r++) S[n][r] = __expf(S[n][r] - mn);
        f32x4 ssv = S[0];
#pragma unroll
        for (int n = 1; n < 4; n++) ssv += S[n];
        float ssum = (ssv[0] + ssv[1]) + (ssv[2] + ssv[3]);
        ssum += __shfl_xor(ssum, 16);
        ssum += __shfl_xor(ssum, 32);
        lrow = lrow * scale + ssum;

        // pack P to bf16 pairs: c[n][m] = pack(P[q][16n+4g+2m], P[q][16n+4g+2m+1])
        unsigned c[4][2];
#pragma unroll
        for (int n = 0; n < 4; n++) {
            asm("v_cvt_pk_bf16_f32 %0, %1, %2" : "=v"(c[n][0]) : "v"(S[n][0]), "v"(S[n][1]));
            asm("v_cvt_pk_bf16_f32 %0, %1, %2" : "=v"(c[n][1]) : "v"(S[n][2]), "v"(S[n][3]));
        }
        // redistribute into PV A-frags (frag0: k 0..31, frag1: k 32..63)
        union { unsigned u[4]; s16x8 v; } pf0, pf1;
#pragma unroll
        for (int m = 0; m < 2; m++) {
            unsigned a = c[0][m], bb = c[1][m];
            asm("v_permlane32_swap_b32 %0, %1" : "+v"(a), "+v"(bb));
            asm("v_permlane16_swap_b32 %0, %1" : "+v"(a), "+v"(bb));
            pf0.u[m] = a; pf0.u[2 + m] = bb;
            unsigned a2 = c[2][m], b2 = c[3][m];
            asm("v_permlane32_swap_b32 %0, %1" : "+v"(a2), "+v"(b2));
            asm("v_permlane16_swap_b32 %0, %1" : "+v"(a2), "+v"(b2));
            pf1.u[m] = a2; pf1.u[2 + m] = b2;
        }
        // O rescale: scale lives on lanes keyed by q=lane&15; O rows are q=4g+r
        float sc0 = __shfl(scale, 4 * g + 0);
        float sc1 = __shfl(scale, 4 * g + 1);
        float sc2 = __shfl(scale, 4 * g + 2);
        float sc3 = __shfl(scale, 4 * g + 3);
#pragma unroll
        for (int n = 0; n < 4; n++) {
            O[n][0] *= sc0; O[n][1] *= sc1; O[n][2] *= sc2; O[n][3] *= sc3;
        }
        // PV
#pragma unroll
        for (int n = 0; n < 4; n++) {
            const ushort* vp = vh + (size_t)(n * 16 + lr) * SEQ_ + kbase + g * 8;
            s16x8 v0 = *(const s16x8*)vp;
            s16x8 v1 = *(const s16x8*)(vp + 32);
            O[n] = __builtin_amdgcn_mfma_f32_16x16x32_bf16(pf0.v, v0, O[n], 0, 0, 0);
            O[n] = __builtin_amdgcn_mfma_f32_16x16x32_bf16(pf1.v, v1, O[n], 0, 0, 0);
        }
    }

    const float fin = 0.03608439182435161f; // 1/sqrt(768), applied post-softmax
#pragma unroll
    for (int r = 0; r < 4; r++) {
        float linv = fin / __shfl(lrow, 4 * g + r);
        int row = b * SEQ_ + qt * 64 + w * 16 + 4 * g + r;
        ushort* ao = AO + (size_t)row * DIM_ + h * DH_ + lr;
#pragma unroll
        for (int n = 0; n < 4; n++)
            ao[n * 16] = f2bf(O[n][r] * linv);
    }
}

// ---------------- fused residual + LayerNorm (wave per row, float4) ----------------
__global__ __launch_bounds__(256) void ln_residual_kernel(
    const float* __restrict__ xin, const float* __restrict__ y,
    const float* __restrict__ g, const float* __restrict__ be,
    float* __restrict__ outf, ushort* __restrict__ outbf, int rows)
{
    int w = threadIdx.x >> 6, lane = threadIdx.x & 63;
    int row = blockIdx.x * 4 + w;
    if (row >= rows) return;
    const float4* yr = (const float4*)(y + (size_t)row * DIM_);
    float4 v[3];
    float s = 0.f, s2 = 0.f;
#pragma unroll
    for (int i = 0; i < 3; i++) {
        v[i] = yr[i * 64 + lane];
        s += (v[i].x + v[i].y) + (v[i].z + v[i].w);
        s2 += (v[i].x * v[i].x + v[i].y * v[i].y) + (v[i].z * v[i].z + v[i].w * v[i].w);
    }
#pragma unroll
    for (int o = 1; o < 64; o <<= 1) { s += __shfl_xor(s, o); s2 += __shfl_xor(s2, o); }
    float mu = s * (1.f / 768.f);
    float var = s2 * (1.f / 768.f) - mu * mu;
    float rs = rsqrtf(var + 1e-5f);
    const float4* xr = (const float4*)(xin + (size_t)row * DIM_);
    const float4* g4 = (const float4*)g;
    const float4* b4 = (const float4*)be;
    float4* of = (float4*)(outf + (size_t)row * DIM_);
#pragma unroll
    for (int i = 0; i < 3; i++) {
        int c = i * 64 + lane;
        float4 gg = g4[c], bb = b4[c], xx = xr[c];
        float4 o;
        o.x = xx.x + (v[i].x - mu) * rs * gg.x + bb.x;
        o.y = xx.y + (v[i].y - mu) * rs * gg.y + bb.y;
        o.z = xx.z + (v[i].z - mu) * rs * gg.z + bb.z;
        o.w = xx.w + (v[i].w - mu) * rs * gg.w + bb.w;
        of[c] = o;
        if (outbf) {
            ushort4 ob;
            ob.x = f2bf(o.x); ob.y = f2bf(o.y); ob.z = f2bf(o.z); ob.w = f2bf(o.w);
            ((ushort4*)(outbf + (size_t)row * DIM_))[c] = ob;
        }
    }
}

// ---------------- launch ----------------
extern "C" void kernel_launch(void* const* d_in, const int* in_sizes, int n_in,
                              void* d_out, int out_size, void* d_ws, size_t ws_size,
                              hipStream_t stream)
{
    const float* x    = (const float*)d_in[0];
    const float* Wqkv = (const float*)d_in[1];
    const float* bqkv = (const float*)d_in[2];
    const float* Wproj= (const float*)d_in[3];
    const float* bproj= (const float*)d_in[4];
    const float* W1   = (const float*)d_in[5];
    const float* b1   = (const float*)d_in[6];
    const float* W2   = (const float*)d_in[7];
    const float* b2   = (const float*)d_in[8];
    const float* g1   = (const float*)d_in[9];
    const float* be1  = (const float*)d_in[10];
    const float* g2   = (const float*)d_in[11];
    const float* be2  = (const float*)d_in[12];
    float* out = (float*)d_out;

    char* ws = (char*)d_ws;
    size_t off = 0;
    auto alloc = [&](size_t bytes) -> void* {
        void* p = ws + off;
        off += (bytes + 255) & ~(size_t)255;
        return p;
    };
    ushort* xbf    = (ushort*)alloc((size_t)ROWS_ * DIM_ * 2);
    ushort* wqkvT  = (ushort*)alloc((size_t)2304 * 768 * 2);
    ushort* wprojT = (ushort*)alloc((size_t)768 * 768 * 2);
    ushort* w1T    = (ushort*)alloc((size_t)3072 * 768 * 2);
    ushort* w2T    = (ushort*)alloc((size_t)768 * 3072 * 2);
    ushort* qb     = (ushort*)alloc((size_t)ROWS_ * DIM_ * 2);
    ushort* kb     = (ushort*)alloc((size_t)ROWS_ * DIM_ * 2);
    ushort* vT     = (ushort*)alloc((size_t)ROWS_ * DIM_ * 2);
    ushort* aobf   = (ushort*)alloc((size_t)ROWS_ * DIM_ * 2);
    float*  projf  = (float*) alloc((size_t)ROWS_ * DIM_ * 4);  // reused for mlp_out
    float*  x1f    = (float*) alloc((size_t)ROWS_ * DIM_ * 4);
    ushort* x1bf   = (ushort*)alloc((size_t)ROWS_ * DIM_ * 2);
    ushort* hbf    = (ushort*)alloc((size_t)ROWS_ * HID_ * 2);

    // prep
    cast_bf16_kernel<<<(ROWS_ * DIM_ / 4 + 255) / 256, 256, 0, stream>>>(x, xbf, ROWS_ * DIM_ / 4);
    transpose_cast_kernel<<<dim3(2304 / 32, 768 / 32), dim3(32, 8), 0, stream>>>(Wqkv, wqkvT, 768, 2304);
    transpose_cast_kernel<<<dim3(768 / 32, 768 / 32), dim3(32, 8), 0, stream>>>(Wproj, wprojT, 768, 768);
    transpose_cast_kernel<<<dim3(3072 / 32, 768 / 32), dim3(32, 8), 0, stream>>>(W1, w1T, 768, 3072);
    transpose_cast_kernel<<<dim3(768 / 32, 3072 / 32), dim3(32, 8), 0, stream>>>(W2, w2T, 3072, 768);

    // qkv = x @ Wqkv + bqkv  -> scatter into q/k/vT
    gemm_bt<EPI_QKV><<<dim3(2304 / 128, ROWS_ / 128), 256, 0, stream>>>(
        xbf, wqkvT, bqkv, nullptr, nullptr, qb, kb, vT, ROWS_, 2304, 768);

    // attention -> aobf [8192][768]
    attn_kernel<<<dim3(SEQ_ / 64, BATCH_ * HEADS_), 256, 0, stream>>>(qb, kb, vT, aobf);

    // proj
    gemm_bt<EPI_F32><<<dim3(768 / 128, ROWS_ / 128), 256, 0, stream>>>(
        aobf, wprojT, bproj, projf, nullptr, nullptr, nullptr, nullptr, ROWS_, 768, 768);

    // x1 = x + LN(proj)
    ln_residual_kernel<<<ROWS_ / 4, 256, 0, stream>>>(x, projf, g1, be1, x1f, x1bf, ROWS_);

    // h = gelu(x1 @ W1 + b1)
    gemm_bt<EPI_GELU><<<dim3(3072 / 128, ROWS_ / 128), 256, 0, stream>>>(
        x1bf, w1T, b1, nullptr, hbf, nullptr, nullptr, nullptr, ROWS_, 3072, 768);

    // mlp = h @ W2 + b2 (reuse projf)
    gemm_bt<EPI_F32><<<dim3(768 / 128, ROWS_ / 128), 256, 0, stream>>>(
        hbf, w2T, b2, projf, nullptr, nullptr, nullptr, nullptr, ROWS_, 768, 3072);

    // out = x1 + LN(mlp)
    ln_residual_kernel<<<ROWS_ / 4, 256, 0, stream>>>(x1f, projf, g2, be2, out, nullptr, ROWS_);
}

// Round 4
// 369.185 us; speedup vs baseline: 1.2390x; 1.2176x over previous
//
#include <hip/hip_runtime.h>
#include <math.h>

typedef float f32x4 __attribute__((ext_vector_type(4)));
typedef short s16x8 __attribute__((ext_vector_type(8)));

#define DIM_ 768
#define HEADS_ 12
#define DH_ 64
#define HID_ 3072
#define SEQ_ 1024
#define BATCH_ 8
#define ROWS_ (BATCH_*SEQ_)   // 8192

static __device__ __forceinline__ ushort f2bf(float f) {
    union { float f; unsigned u; } v; v.f = f;
    unsigned r = (v.u + 0x7fffu + ((v.u >> 16) & 1u)) >> 16;
    return (ushort)r;
}

static __device__ __forceinline__ void glds16(const ushort* gp, ushort* lp) {
    __builtin_amdgcn_global_load_lds(
        (const __attribute__((address_space(1))) void*)gp,
        (__attribute__((address_space(3))) void*)lp, 16, 0, 0);
}

// ---------------- prep: cast x to bf16 ----------------
__global__ __launch_bounds__(256) void cast_bf16_kernel(
    const float* __restrict__ in, ushort* __restrict__ out, int n4)
{
    int i = blockIdx.x * 256 + threadIdx.x;
    if (i >= n4) return;
    float4 v = ((const float4*)in)[i];
    ushort4 o;
    o.x = f2bf(v.x); o.y = f2bf(v.y); o.z = f2bf(v.z); o.w = f2bf(v.w);
    ((ushort4*)out)[i] = o;
}

// ---------------- prep: transpose+cast W[K][N] -> WT[N][K] bf16 ----------------
__global__ __launch_bounds__(256) void transpose_cast_kernel(
    const float* __restrict__ W, ushort* __restrict__ WT, int K, int N)
{
    __shared__ float tile[32][33];
    int n0 = blockIdx.x * 32, k0 = blockIdx.y * 32;
    int tx = threadIdx.x, ty = threadIdx.y; // 32 x 8
#pragma unroll
    for (int i = 0; i < 4; i++)
        tile[ty + i * 8][tx] = W[(size_t)(k0 + ty + i * 8) * N + n0 + tx];
    __syncthreads();
#pragma unroll
    for (int i = 0; i < 4; i++)
        WT[(size_t)(n0 + ty + i * 8) * K + k0 + tx] = f2bf(tile[tx][ty + i * 8]);
}

// ---------------- GEMM: C[M][N] = A[M][K](bf16) @ BT[N][K](bf16)^T + bias ----------------
#define EPI_F32 0
#define EPI_GELU 1
#define EPI_QKV 2

template<int EPI>
__global__ __launch_bounds__(256, 2) void gemm_bt(
    const ushort* __restrict__ A, const ushort* __restrict__ B,
    const float* __restrict__ bias,
    float* __restrict__ Cf, ushort* __restrict__ Cbf,
    ushort* __restrict__ Qb, ushort* __restrict__ Kb, ushort* __restrict__ Vt,
    int M, int N, int K)
{
    __shared__ ushort As[128 * 32];
    __shared__ ushort Bs[128 * 32];
    const int t = threadIdx.x;
    const int lane = t & 63;
    const int w = t >> 6;
    const int wr = w >> 1, wc = w & 1;
    const int m0 = blockIdx.y * 128, n0 = blockIdx.x * 128;
    const int lr = lane & 15, lk = (lane >> 4) * 8;

    const int srow = lane >> 2, scol = (lane & 3) * 8;
    const ushort* Ag0 = A + (size_t)(m0 + w * 16 + srow) * K + scol;
    const ushort* Ag1 = A + (size_t)(m0 + 64 + w * 16 + srow) * K + scol;
    const ushort* Bg0 = B + (size_t)(n0 + w * 16 + srow) * K + scol;
    const ushort* Bg1 = B + (size_t)(n0 + 64 + w * 16 + srow) * K + scol;
    ushort* as0 = &As[(w * 16) * 32];
    ushort* as1 = &As[(64 + w * 16) * 32];
    ushort* bs0 = &Bs[(w * 16) * 32];
    ushort* bs1 = &Bs[(64 + w * 16) * 32];

    f32x4 acc[4][4] = {};

    for (int k0 = 0; k0 < K; k0 += 32) {
        glds16(Ag0 + k0, as0);
        glds16(Ag1 + k0, as1);
        glds16(Bg0 + k0, bs0);
        glds16(Bg1 + k0, bs1);
        __syncthreads();
        s16x8 af[4], bfr[4];
#pragma unroll
        for (int m = 0; m < 4; m++)
            af[m] = *(const s16x8*)&As[(wr * 64 + m * 16 + lr) * 32 + lk];
#pragma unroll
        for (int n = 0; n < 4; n++)
            bfr[n] = *(const s16x8*)&Bs[(wc * 64 + n * 16 + lr) * 32 + lk];
#pragma unroll
        for (int m = 0; m < 4; m++)
#pragma unroll
            for (int n = 0; n < 4; n++)
                acc[m][n] = __builtin_amdgcn_mfma_f32_16x16x32_bf16(af[m], bfr[n], acc[m][n], 0, 0, 0);
        __syncthreads();
    }

#pragma unroll
    for (int m = 0; m < 4; m++) {
        int row = m0 + wr * 64 + m * 16 + (lane >> 4) * 4;
#pragma unroll
        for (int n = 0; n < 4; n++) {
            int col = n0 + wc * 64 + n * 16 + lr;
            float bv = bias[col];
#pragma unroll
            for (int r = 0; r < 4; r++) {
                float v = acc[m][n][r] + bv;
                int rg = row + r;
                if (EPI == EPI_F32) {
                    Cf[(size_t)rg * N + col] = v;
                } else if (EPI == EPI_GELU) {
                    float gl = 0.5f * v * (1.0f + erff(v * 0.70710678118654752f));
                    Cbf[(size_t)rg * N + col] = f2bf(gl);
                } else { // QKV scatter: col = h*192 + dh*3 + which
                    int b = rg >> 10, nrow = rg & 1023;
                    int h = col / 192, rem = col % 192;
                    int dh = rem / 3, wh = rem % 3;
                    int hb = b * HEADS_ + h;
                    ushort bw = f2bf(v);
                    if (wh == 0)      Qb[((size_t)hb * SEQ_ + nrow) * DH_ + dh] = bw;
                    else if (wh == 1) Kb[((size_t)hb * SEQ_ + nrow) * DH_ + dh] = bw;
                    else              Vt[(size_t)hb * DH_ * SEQ_ + (size_t)dh * SEQ_ + nrow] = bw;
                }
            }
        }
    }
}

// ---- softmax + pack + permlane redistribution for one 16-q fragment ----
// S[n][r] = scores for q=lr, k=kbase+16n+4g+r. Produces PV A-frags pf0 (k 0..31),
// pf1 (k 32..63), updates running max/sum, returns rescale factor (keyed by q=lr).
static __device__ __forceinline__ void softmax_pack(
    f32x4 (&S)[4], float& mrow, float& lrow, float& scale,
    s16x8& pf0v, s16x8& pf1v)
{
    f32x4 mm = S[0];
#pragma unroll
    for (int n = 1; n < 4; n++) {
#pragma unroll
        for (int r = 0; r < 4; r++) mm[r] = fmaxf(mm[r], S[n][r]);
    }
    float mx = fmaxf(fmaxf(mm[0], mm[1]), fmaxf(mm[2], mm[3]));
    mx = fmaxf(mx, __shfl_xor(mx, 16));
    mx = fmaxf(mx, __shfl_xor(mx, 32));
    float mn = fmaxf(mrow, mx);
    scale = __expf(mrow - mn);
    mrow = mn;
#pragma unroll
    for (int n = 0; n < 4; n++)
#pragma unroll
        for (int r = 0; r < 4; r++) S[n][r] = __expf(S[n][r] - mn);
    f32x4 ssv = S[0];
#pragma unroll
    for (int n = 1; n < 4; n++) ssv += S[n];
    float ssum = (ssv[0] + ssv[1]) + (ssv[2] + ssv[3]);
    ssum += __shfl_xor(ssum, 16);
    ssum += __shfl_xor(ssum, 32);
    lrow = lrow * scale + ssum;

    unsigned c[4][2];
#pragma unroll
    for (int n = 0; n < 4; n++) {
        asm("v_cvt_pk_bf16_f32 %0, %1, %2" : "=v"(c[n][0]) : "v"(S[n][0]), "v"(S[n][1]));
        asm("v_cvt_pk_bf16_f32 %0, %1, %2" : "=v"(c[n][1]) : "v"(S[n][2]), "v"(S[n][3]));
    }
    union { unsigned u[4]; s16x8 v; } pf0, pf1;
#pragma unroll
    for (int m = 0; m < 2; m++) {
        unsigned a = c[0][m], bb = c[1][m];
        asm("v_permlane32_swap_b32 %0, %1" : "+v"(a), "+v"(bb));
        asm("v_permlane16_swap_b32 %0, %1" : "+v"(a), "+v"(bb));
        pf0.u[m] = a; pf0.u[2 + m] = bb;
        unsigned a2 = c[2][m], b2 = c[3][m];
        asm("v_permlane32_swap_b32 %0, %1" : "+v"(a2), "+v"(b2));
        asm("v_permlane16_swap_b32 %0, %1" : "+v"(a2), "+v"(b2));
        pf1.u[m] = a2; pf1.u[2 + m] = b2;
    }
    pf0v = pf0.v; pf1v = pf1.v;
}

// ---------------- flash attention v2: 32 q/wave, K reg-prefetch ----------------
// Q,K: [b*h][1024][64] bf16 ; Vt: [b*h][64][1024] bf16 ; AO: [8192][768] bf16
__global__ __launch_bounds__(256) void attn_kernel(
    const ushort* __restrict__ Q, const ushort* __restrict__ Kb,
    const ushort* __restrict__ Vt, ushort* __restrict__ AO)
{
    const int t = threadIdx.x, lane = t & 63, w = t >> 6;
    const int lr = lane & 15, g = lane >> 4;
    const int qt = blockIdx.x;   // 0..7 (128 q-rows per block)
    const int bh = blockIdx.y;   // 0..95
    const int b = bh / HEADS_, h = bh % HEADS_;
    const ushort* qh = Q + (size_t)bh * SEQ_ * DH_;
    const ushort* kh = Kb + (size_t)bh * SEQ_ * DH_;
    const ushort* vh = Vt + (size_t)bh * DH_ * SEQ_;

    const int qbase = qt * 128 + w * 32;
    // Q fragments (B operand): col=lr=q_local, k-elem dh = g*8+j
    s16x8 aqA0 = *(const s16x8*)(qh + (size_t)(qbase + lr) * DH_ + g * 8);
    s16x8 aqA1 = *(const s16x8*)(qh + (size_t)(qbase + lr) * DH_ + 32 + g * 8);
    s16x8 aqB0 = *(const s16x8*)(qh + (size_t)(qbase + 16 + lr) * DH_ + g * 8);
    s16x8 aqB1 = *(const s16x8*)(qh + (size_t)(qbase + 16 + lr) * DH_ + 32 + g * 8);

    float mA = -INFINITY, lA = 0.f, mB = -INFINITY, lB = 0.f;
    f32x4 OA[4] = {}, OB[4] = {};

    // K fragment regs: kc[2n+half] covers K rows kbase+16n+lr, dh half
    s16x8 kc[8], kn[8];
#pragma unroll
    for (int n = 0; n < 4; n++) {
        const ushort* kp = kh + (size_t)(n * 16 + lr) * DH_ + g * 8;
        kc[2 * n]     = *(const s16x8*)kp;
        kc[2 * n + 1] = *(const s16x8*)(kp + 32);
    }

    for (int tkv = 0; tkv < 16; ++tkv) {
        const int kbase = tkv * 64;
        // prefetch next tile's K into kn (latency hides under this tile's work)
        if (tkv < 15) {
#pragma unroll
            for (int n = 0; n < 4; n++) {
                const ushort* kp = kh + (size_t)(kbase + 64 + n * 16 + lr) * DH_ + g * 8;
                kn[2 * n]     = *(const s16x8*)kp;
                kn[2 * n + 1] = *(const s16x8*)(kp + 32);
            }
        }
        // QK^T frag A
        f32x4 SA[4] = {};
#pragma unroll
        for (int n = 0; n < 4; n++) {
            SA[n] = __builtin_amdgcn_mfma_f32_16x16x32_bf16(kc[2 * n], aqA0, SA[n], 0, 0, 0);
            SA[n] = __builtin_amdgcn_mfma_f32_16x16x32_bf16(kc[2 * n + 1], aqA1, SA[n], 0, 0, 0);
        }
        // V loads for this tile (latency hides under the two softmaxes)
        s16x8 vf[8];
#pragma unroll
        for (int n = 0; n < 4; n++) {
            const ushort* vp = vh + (size_t)(n * 16 + lr) * SEQ_ + kbase + g * 8;
            vf[2 * n]     = *(const s16x8*)vp;
            vf[2 * n + 1] = *(const s16x8*)(vp + 32);
        }
        // QK^T frag B (independent of softmax A -> MFMA/VALU overlap)
        f32x4 SB[4] = {};
#pragma unroll
        for (int n = 0; n < 4; n++) {
            SB[n] = __builtin_amdgcn_mfma_f32_16x16x32_bf16(kc[2 * n], aqB0, SB[n], 0, 0, 0);
            SB[n] = __builtin_amdgcn_mfma_f32_16x16x32_bf16(kc[2 * n + 1], aqB1, SB[n], 0, 0, 0);
        }
        float scA, scB;
        s16x8 pfA0, pfA1, pfB0, pfB1;
        softmax_pack(SA, mA, lA, scA, pfA0, pfA1);
        softmax_pack(SB, mB, lB, scB, pfB0, pfB1);
        // O rescale (scale keyed by q=lr; O rows are q=4g+r)
        float a0 = __shfl(scA, 4 * g + 0), a1 = __shfl(scA, 4 * g + 1);
        float a2 = __shfl(scA, 4 * g + 2), a3 = __shfl(scA, 4 * g + 3);
        float b0 = __shfl(scB, 4 * g + 0), b1 = __shfl(scB, 4 * g + 1);
        float b2 = __shfl(scB, 4 * g + 2), b3 = __shfl(scB, 4 * g + 3);
#pragma unroll
        for (int n = 0; n < 4; n++) {
            OA[n][0] *= a0; OA[n][1] *= a1; OA[n][2] *= a2; OA[n][3] *= a3;
            OB[n][0] *= b0; OB[n][1] *= b1; OB[n][2] *= b2; OB[n][3] *= b3;
        }
        // PV
        __builtin_amdgcn_s_setprio(1);
#pragma unroll
        for (int n = 0; n < 4; n++) {
            OA[n] = __builtin_amdgcn_mfma_f32_16x16x32_bf16(pfA0, vf[2 * n], OA[n], 0, 0, 0);
            OA[n] = __builtin_amdgcn_mfma_f32_16x16x32_bf16(pfA1, vf[2 * n + 1], OA[n], 0, 0, 0);
        }
#pragma unroll
        for (int n = 0; n < 4; n++) {
            OB[n] = __builtin_amdgcn_mfma_f32_16x16x32_bf16(pfB0, vf[2 * n], OB[n], 0, 0, 0);
            OB[n] = __builtin_amdgcn_mfma_f32_16x16x32_bf16(pfB1, vf[2 * n + 1], OB[n], 0, 0, 0);
        }
        __builtin_amdgcn_s_setprio(0);
#pragma unroll
        for (int i = 0; i < 8; i++) kc[i] = kn[i];
    }

    const float fin = 0.03608439182435161f; // 1/sqrt(768), applied post-softmax
#pragma unroll
    for (int r = 0; r < 4; r++) {
        float linvA = fin / __shfl(lA, 4 * g + r);
        float linvB = fin / __shfl(lB, 4 * g + r);
        int rowA = b * SEQ_ + qbase + 4 * g + r;
        int rowB = rowA + 16;
        ushort* aoA = AO + (size_t)rowA * DIM_ + h * DH_ + lr;
        ushort* aoB = AO + (size_t)rowB * DIM_ + h * DH_ + lr;
#pragma unroll
        for (int n = 0; n < 4; n++) {
            aoA[n * 16] = f2bf(OA[n][r] * linvA);
            aoB[n * 16] = f2bf(OB[n][r] * linvB);
        }
    }
}

// ---------------- fused residual + LayerNorm (wave per row, float4) ----------------
__global__ __launch_bounds__(256) void ln_residual_kernel(
    const float* __restrict__ xin, const float* __restrict__ y,
    const float* __restrict__ g, const float* __restrict__ be,
    float* __restrict__ outf, ushort* __restrict__ outbf, int rows)
{
    int w = threadIdx.x >> 6, lane = threadIdx.x & 63;
    int row = blockIdx.x * 4 + w;
    if (row >= rows) return;
    const float4* yr = (const float4*)(y + (size_t)row * DIM_);
    float4 v[3];
    float s = 0.f, s2 = 0.f;
#pragma unroll
    for (int i = 0; i < 3; i++) {
        v[i] = yr[i * 64 + lane];
        s += (v[i].x + v[i].y) + (v[i].z + v[i].w);
        s2 += (v[i].x * v[i].x + v[i].y * v[i].y) + (v[i].z * v[i].z + v[i].w * v[i].w);
    }
#pragma unroll
    for (int o = 1; o < 64; o <<= 1) { s += __shfl_xor(s, o); s2 += __shfl_xor(s2, o); }
    float mu = s * (1.f / 768.f);
    float var = s2 * (1.f / 768.f) - mu * mu;
    float rs = rsqrtf(var + 1e-5f);
    const float4* xr = (const float4*)(xin + (size_t)row * DIM_);
    const float4* g4 = (const float4*)g;
    const float4* b4 = (const float4*)be;
    float4* of = (float4*)(outf + (size_t)row * DIM_);
#pragma unroll
    for (int i = 0; i < 3; i++) {
        int c = i * 64 + lane;
        float4 gg = g4[c], bb = b4[c], xx = xr[c];
        float4 o;
        o.x = xx.x + (v[i].x - mu) * rs * gg.x + bb.x;
        o.y = xx.y + (v[i].y - mu) * rs * gg.y + bb.y;
        o.z = xx.z + (v[i].z - mu) * rs * gg.z + bb.z;
        o.w = xx.w + (v[i].w - mu) * rs * gg.w + bb.w;
        of[c] = o;
        if (outbf) {
            ushort4 ob;
            ob.x = f2bf(o.x); ob.y = f2bf(o.y); ob.z = f2bf(o.z); ob.w = f2bf(o.w);
            ((ushort4*)(outbf + (size_t)row * DIM_))[c] = ob;
        }
    }
}

// ---------------- launch ----------------
extern "C" void kernel_launch(void* const* d_in, const int* in_sizes, int n_in,
                              void* d_out, int out_size, void* d_ws, size_t ws_size,
                              hipStream_t stream)
{
    const float* x    = (const float*)d_in[0];
    const float* Wqkv = (const float*)d_in[1];
    const float* bqkv = (const float*)d_in[2];
    const float* Wproj= (const float*)d_in[3];
    const float* bproj= (const float*)d_in[4];
    const float* W1   = (const float*)d_in[5];
    const float* b1   = (const float*)d_in[6];
    const float* W2   = (const float*)d_in[7];
    const float* b2   = (const float*)d_in[8];
    const float* g1   = (const float*)d_in[9];
    const float* be1  = (const float*)d_in[10];
    const float* g2   = (const float*)d_in[11];
    const float* be2  = (const float*)d_in[12];
    float* out = (float*)d_out;

    char* ws = (char*)d_ws;
    size_t off = 0;
    auto alloc = [&](size_t bytes) -> void* {
        void* p = ws + off;
        off += (bytes + 255) & ~(size_t)255;
        return p;
    };
    ushort* xbf    = (ushort*)alloc((size_t)ROWS_ * DIM_ * 2);
    ushort* wqkvT  = (ushort*)alloc((size_t)2304 * 768 * 2);
    ushort* wprojT = (ushort*)alloc((size_t)768 * 768 * 2);
    ushort* w1T    = (ushort*)alloc((size_t)3072 * 768 * 2);
    ushort* w2T    = (ushort*)alloc((size_t)768 * 3072 * 2);
    ushort* qb     = (ushort*)alloc((size_t)ROWS_ * DIM_ * 2);
    ushort* kb     = (ushort*)alloc((size_t)ROWS_ * DIM_ * 2);
    ushort* vT     = (ushort*)alloc((size_t)ROWS_ * DIM_ * 2);
    ushort* aobf   = (ushort*)alloc((size_t)ROWS_ * DIM_ * 2);
    float*  projf  = (float*) alloc((size_t)ROWS_ * DIM_ * 4);  // reused for mlp_out
    float*  x1f    = (float*) alloc((size_t)ROWS_ * DIM_ * 4);
    ushort* x1bf   = (ushort*)alloc((size_t)ROWS_ * DIM_ * 2);
    ushort* hbf    = (ushort*)alloc((size_t)ROWS_ * HID_ * 2);

    // prep
    cast_bf16_kernel<<<(ROWS_ * DIM_ / 4 + 255) / 256, 256, 0, stream>>>(x, xbf, ROWS_ * DIM_ / 4);
    transpose_cast_kernel<<<dim3(2304 / 32, 768 / 32), dim3(32, 8), 0, stream>>>(Wqkv, wqkvT, 768, 2304);
    transpose_cast_kernel<<<dim3(768 / 32, 768 / 32), dim3(32, 8), 0, stream>>>(Wproj, wprojT, 768, 768);
    transpose_cast_kernel<<<dim3(3072 / 32, 768 / 32), dim3(32, 8), 0, stream>>>(W1, w1T, 768, 3072);
    transpose_cast_kernel<<<dim3(768 / 32, 3072 / 32), dim3(32, 8), 0, stream>>>(W2, w2T, 3072, 768);

    // qkv = x @ Wqkv + bqkv  -> scatter into q/k/vT
    gemm_bt<EPI_QKV><<<dim3(2304 / 128, ROWS_ / 128), 256, 0, stream>>>(
        xbf, wqkvT, bqkv, nullptr, nullptr, qb, kb, vT, ROWS_, 2304, 768);

    // attention -> aobf [8192][768]
    attn_kernel<<<dim3(SEQ_ / 128, BATCH_ * HEADS_), 256, 0, stream>>>(qb, kb, vT, aobf);

    // proj
    gemm_bt<EPI_F32><<<dim3(768 / 128, ROWS_ / 128), 256, 0, stream>>>(
        aobf, wprojT, bproj, projf, nullptr, nullptr, nullptr, nullptr, ROWS_, 768, 768);

    // x1 = x + LN(proj)
    ln_residual_kernel<<<ROWS_ / 4, 256, 0, stream>>>(x, projf, g1, be1, x1f, x1bf, ROWS_);

    // h = gelu(x1 @ W1 + b1)
    gemm_bt<EPI_GELU><<<dim3(3072 / 128, ROWS_ / 128), 256, 0, stream>>>(
        x1bf, w1T, b1, nullptr, hbf, nullptr, nullptr, nullptr, ROWS_, 3072, 768);

    // mlp = h @ W2 + b2 (reuse projf)
    gemm_bt<EPI_F32><<<dim3(768 / 128, ROWS_ / 128), 256, 0, stream>>>(
        hbf, w2T, b2, projf, nullptr, nullptr, nullptr, nullptr, ROWS_, 768, 3072);

    // out = x1 + LN(mlp)
    ln_residual_kernel<<<ROWS_ / 4, 256, 0, stream>>>(x1f, projf, g2, be2, out, nullptr, ROWS_);
}

// Round 5
// 358.240 us; speedup vs baseline: 1.2768x; 1.0306x over previous
//
#include <hip/hip_runtime.h>
#include <math.h>

typedef float f32x4 __attribute__((ext_vector_type(4)));
typedef short s16x8 __attribute__((ext_vector_type(8)));

#define DIM_ 768
#define HEADS_ 12
#define DH_ 64
#define HID_ 3072
#define SEQ_ 1024
#define BATCH_ 8
#define ROWS_ (BATCH_*SEQ_)   // 8192

static __device__ __forceinline__ ushort f2bf(float f) {
    union { float f; unsigned u; } v; v.f = f;
    unsigned r = (v.u + 0x7fffu + ((v.u >> 16) & 1u)) >> 16;
    return (ushort)r;
}

static __device__ __forceinline__ void glds16(const ushort* gp, ushort* lp) {
    __builtin_amdgcn_global_load_lds(
        (const __attribute__((address_space(1))) void*)gp,
        (__attribute__((address_space(3))) void*)lp, 16, 0, 0);
}

// ---------------- prep: cast x to bf16 ----------------
__global__ __launch_bounds__(256) void cast_bf16_kernel(
    const float* __restrict__ in, ushort* __restrict__ out, int n4)
{
    int i = blockIdx.x * 256 + threadIdx.x;
    if (i >= n4) return;
    float4 v = ((const float4*)in)[i];
    ushort4 o;
    o.x = f2bf(v.x); o.y = f2bf(v.y); o.z = f2bf(v.z); o.w = f2bf(v.w);
    ((ushort4*)out)[i] = o;
}

// ---------------- prep: transpose+cast W[K][N] -> WT[N][K] bf16 ----------------
__global__ __launch_bounds__(256) void transpose_cast_kernel(
    const float* __restrict__ W, ushort* __restrict__ WT, int K, int N)
{
    __shared__ float tile[32][33];
    int n0 = blockIdx.x * 32, k0 = blockIdx.y * 32;
    int tx = threadIdx.x, ty = threadIdx.y; // 32 x 8
#pragma unroll
    for (int i = 0; i < 4; i++)
        tile[ty + i * 8][tx] = W[(size_t)(k0 + ty + i * 8) * N + n0 + tx];
    __syncthreads();
#pragma unroll
    for (int i = 0; i < 4; i++)
        WT[(size_t)(n0 + ty + i * 8) * K + k0 + tx] = f2bf(tile[tx][ty + i * 8]);
}

// ---------------- GEMM: C[M][N] = A[M][K](bf16) @ BT[N][K](bf16)^T + bias ----------------
// 1D grid + XCD-aware swizzle: each XCD gets a contiguous chunk of (mt-major,
// nt-fastest) tiles so A row-panels are fetched once per XCD, not 8x.
#define EPI_F32 0
#define EPI_GELU 1
#define EPI_QKV 2

template<int EPI>
__global__ __launch_bounds__(256, 2) void gemm_bt(
    const ushort* __restrict__ A, const ushort* __restrict__ B,
    const float* __restrict__ bias,
    float* __restrict__ Cf, ushort* __restrict__ Cbf,
    ushort* __restrict__ Qb, ushort* __restrict__ Kb, ushort* __restrict__ Vt,
    int M, int N, int K, int nx)
{
    __shared__ ushort As[128 * 32];
    __shared__ ushort Bs[128 * 32];
    const int t = threadIdx.x;
    const int lane = t & 63;
    const int w = t >> 6;
    const int wr = w >> 1, wc = w & 1;
    // XCD swizzle (nwg % 8 == 0 for all our launches)
    const int nwg = gridDim.x;
    const int chunk = nwg >> 3;
    const int lin = (blockIdx.x & 7) * chunk + (blockIdx.x >> 3);
    const int m0 = (lin / nx) * 128, n0 = (lin % nx) * 128;
    const int lr = lane & 15, lk = (lane >> 4) * 8;

    const int srow = lane >> 2, scol = (lane & 3) * 8;
    const ushort* Ag0 = A + (size_t)(m0 + w * 16 + srow) * K + scol;
    const ushort* Ag1 = A + (size_t)(m0 + 64 + w * 16 + srow) * K + scol;
    const ushort* Bg0 = B + (size_t)(n0 + w * 16 + srow) * K + scol;
    const ushort* Bg1 = B + (size_t)(n0 + 64 + w * 16 + srow) * K + scol;
    ushort* as0 = &As[(w * 16) * 32];
    ushort* as1 = &As[(64 + w * 16) * 32];
    ushort* bs0 = &Bs[(w * 16) * 32];
    ushort* bs1 = &Bs[(64 + w * 16) * 32];

    f32x4 acc[4][4] = {};

    for (int k0 = 0; k0 < K; k0 += 32) {
        glds16(Ag0 + k0, as0);
        glds16(Ag1 + k0, as1);
        glds16(Bg0 + k0, bs0);
        glds16(Bg1 + k0, bs1);
        __syncthreads();
        s16x8 af[4], bfr[4];
#pragma unroll
        for (int m = 0; m < 4; m++)
            af[m] = *(const s16x8*)&As[(wr * 64 + m * 16 + lr) * 32 + lk];
#pragma unroll
        for (int n = 0; n < 4; n++)
            bfr[n] = *(const s16x8*)&Bs[(wc * 64 + n * 16 + lr) * 32 + lk];
#pragma unroll
        for (int m = 0; m < 4; m++)
#pragma unroll
            for (int n = 0; n < 4; n++)
                acc[m][n] = __builtin_amdgcn_mfma_f32_16x16x32_bf16(af[m], bfr[n], acc[m][n], 0, 0, 0);
        __syncthreads();
    }

#pragma unroll
    for (int m = 0; m < 4; m++) {
        int row = m0 + wr * 64 + m * 16 + (lane >> 4) * 4;
#pragma unroll
        for (int n = 0; n < 4; n++) {
            int col = n0 + wc * 64 + n * 16 + lr;
            float bv = bias[col];
#pragma unroll
            for (int r = 0; r < 4; r++) {
                float v = acc[m][n][r] + bv;
                int rg = row + r;
                if (EPI == EPI_F32) {
                    Cf[(size_t)rg * N + col] = v;
                } else if (EPI == EPI_GELU) {
                    float gl = 0.5f * v * (1.0f + erff(v * 0.70710678118654752f));
                    Cbf[(size_t)rg * N + col] = f2bf(gl);
                } else { // QKV scatter: col = h*192 + dh*3 + which
                    int b = rg >> 10, nrow = rg & 1023;
                    int h = col / 192, rem = col % 192;
                    int dh = rem / 3, wh = rem % 3;
                    int hb = b * HEADS_ + h;
                    ushort bw = f2bf(v);
                    if (wh == 0)      Qb[((size_t)hb * SEQ_ + nrow) * DH_ + dh] = bw;
                    else if (wh == 1) Kb[((size_t)hb * SEQ_ + nrow) * DH_ + dh] = bw;
                    else              Vt[(size_t)hb * DH_ * SEQ_ + (size_t)dh * SEQ_ + nrow] = bw;
                }
            }
        }
    }
}

// ---- softmax + pack + permlane redistribution for one 16-q fragment ----
static __device__ __forceinline__ void softmax_pack(
    f32x4 (&S)[4], float& mrow, float& lrow, float& scale,
    s16x8& pf0v, s16x8& pf1v)
{
    f32x4 mm = S[0];
#pragma unroll
    for (int n = 1; n < 4; n++) {
#pragma unroll
        for (int r = 0; r < 4; r++) mm[r] = fmaxf(mm[r], S[n][r]);
    }
    float mx = fmaxf(fmaxf(mm[0], mm[1]), fmaxf(mm[2], mm[3]));
    mx = fmaxf(mx, __shfl_xor(mx, 16));
    mx = fmaxf(mx, __shfl_xor(mx, 32));
    float mn = fmaxf(mrow, mx);
    scale = __expf(mrow - mn);
    mrow = mn;
#pragma unroll
    for (int n = 0; n < 4; n++)
#pragma unroll
        for (int r = 0; r < 4; r++) S[n][r] = __expf(S[n][r] - mn);
    f32x4 ssv = S[0];
#pragma unroll
    for (int n = 1; n < 4; n++) ssv += S[n];
    float ssum = (ssv[0] + ssv[1]) + (ssv[2] + ssv[3]);
    ssum += __shfl_xor(ssum, 16);
    ssum += __shfl_xor(ssum, 32);
    lrow = lrow * scale + ssum;

    unsigned c[4][2];
#pragma unroll
    for (int n = 0; n < 4; n++) {
        asm("v_cvt_pk_bf16_f32 %0, %1, %2" : "=v"(c[n][0]) : "v"(S[n][0]), "v"(S[n][1]));
        asm("v_cvt_pk_bf16_f32 %0, %1, %2" : "=v"(c[n][1]) : "v"(S[n][2]), "v"(S[n][3]));
    }
    union { unsigned u[4]; s16x8 v; } pf0, pf1;
#pragma unroll
    for (int m = 0; m < 2; m++) {
        unsigned a = c[0][m], bb = c[1][m];
        asm("v_permlane32_swap_b32 %0, %1" : "+v"(a), "+v"(bb));
        asm("v_permlane16_swap_b32 %0, %1" : "+v"(a), "+v"(bb));
        pf0.u[m] = a; pf0.u[2 + m] = bb;
        unsigned a2 = c[2][m], b2 = c[3][m];
        asm("v_permlane32_swap_b32 %0, %1" : "+v"(a2), "+v"(b2));
        asm("v_permlane16_swap_b32 %0, %1" : "+v"(a2), "+v"(b2));
        pf1.u[m] = a2; pf1.u[2 + m] = b2;
    }
    pf0v = pf0.v; pf1v = pf1.v;
}

// ---------------- flash attention v3: 32 q/wave, K reg-prefetch, XCD-local heads ----
// Q,K: [b*h][1024][64] bf16 ; Vt: [b*h][64][1024] bf16 ; AO: [8192][768] bf16
// 1D grid of 768; swizzle so each XCD owns 12 complete heads -> K/V L2-resident.
__global__ __launch_bounds__(256) void attn_kernel(
    const ushort* __restrict__ Q, const ushort* __restrict__ Kb,
    const ushort* __restrict__ Vt, ushort* __restrict__ AO)
{
    const int t = threadIdx.x, lane = t & 63, w = t >> 6;
    const int lr = lane & 15, g = lane >> 4;
    const int wg = blockIdx.x;                 // 0..767
    const int lin = (wg & 7) * 96 + (wg >> 3); // XCD-contiguous work id
    const int bh = lin >> 3;                   // 0..95 (12 heads per XCD)
    const int qt = lin & 7;                    // 0..7
    const int b = bh / HEADS_, h = bh % HEADS_;
    const ushort* qh = Q + (size_t)bh * SEQ_ * DH_;
    const ushort* kh = Kb + (size_t)bh * SEQ_ * DH_;
    const ushort* vh = Vt + (size_t)bh * DH_ * SEQ_;

    const int qbase = qt * 128 + w * 32;
    s16x8 aqA0 = *(const s16x8*)(qh + (size_t)(qbase + lr) * DH_ + g * 8);
    s16x8 aqA1 = *(const s16x8*)(qh + (size_t)(qbase + lr) * DH_ + 32 + g * 8);
    s16x8 aqB0 = *(const s16x8*)(qh + (size_t)(qbase + 16 + lr) * DH_ + g * 8);
    s16x8 aqB1 = *(const s16x8*)(qh + (size_t)(qbase + 16 + lr) * DH_ + 32 + g * 8);

    float mA = -INFINITY, lA = 0.f, mB = -INFINITY, lB = 0.f;
    f32x4 OA[4] = {}, OB[4] = {};

    s16x8 kc[8], kn[8];
#pragma unroll
    for (int n = 0; n < 4; n++) {
        const ushort* kp = kh + (size_t)(n * 16 + lr) * DH_ + g * 8;
        kc[2 * n]     = *(const s16x8*)kp;
        kc[2 * n + 1] = *(const s16x8*)(kp + 32);
    }

    for (int tkv = 0; tkv < 16; ++tkv) {
        const int kbase = tkv * 64;
        if (tkv < 15) {
#pragma unroll
            for (int n = 0; n < 4; n++) {
                const ushort* kp = kh + (size_t)(kbase + 64 + n * 16 + lr) * DH_ + g * 8;
                kn[2 * n]     = *(const s16x8*)kp;
                kn[2 * n + 1] = *(const s16x8*)(kp + 32);
            }
        }
        f32x4 SA[4] = {};
#pragma unroll
        for (int n = 0; n < 4; n++) {
            SA[n] = __builtin_amdgcn_mfma_f32_16x16x32_bf16(kc[2 * n], aqA0, SA[n], 0, 0, 0);
            SA[n] = __builtin_amdgcn_mfma_f32_16x16x32_bf16(kc[2 * n + 1], aqA1, SA[n], 0, 0, 0);
        }
        s16x8 vf[8];
#pragma unroll
        for (int n = 0; n < 4; n++) {
            const ushort* vp = vh + (size_t)(n * 16 + lr) * SEQ_ + kbase + g * 8;
            vf[2 * n]     = *(const s16x8*)vp;
            vf[2 * n + 1] = *(const s16x8*)(vp + 32);
        }
        f32x4 SB[4] = {};
#pragma unroll
        for (int n = 0; n < 4; n++) {
            SB[n] = __builtin_amdgcn_mfma_f32_16x16x32_bf16(kc[2 * n], aqB0, SB[n], 0, 0, 0);
            SB[n] = __builtin_amdgcn_mfma_f32_16x16x32_bf16(kc[2 * n + 1], aqB1, SB[n], 0, 0, 0);
        }
        float scA, scB;
        s16x8 pfA0, pfA1, pfB0, pfB1;
        softmax_pack(SA, mA, lA, scA, pfA0, pfA1);
        softmax_pack(SB, mB, lB, scB, pfB0, pfB1);
        float a0 = __shfl(scA, 4 * g + 0), a1 = __shfl(scA, 4 * g + 1);
        float a2 = __shfl(scA, 4 * g + 2), a3 = __shfl(scA, 4 * g + 3);
        float b0 = __shfl(scB, 4 * g + 0), b1 = __shfl(scB, 4 * g + 1);
        float b2 = __shfl(scB, 4 * g + 2), b3 = __shfl(scB, 4 * g + 3);
#pragma unroll
        for (int n = 0; n < 4; n++) {
            OA[n][0] *= a0; OA[n][1] *= a1; OA[n][2] *= a2; OA[n][3] *= a3;
            OB[n][0] *= b0; OB[n][1] *= b1; OB[n][2] *= b2; OB[n][3] *= b3;
        }
        __builtin_amdgcn_s_setprio(1);
#pragma unroll
        for (int n = 0; n < 4; n++) {
            OA[n] = __builtin_amdgcn_mfma_f32_16x16x32_bf16(pfA0, vf[2 * n], OA[n], 0, 0, 0);
            OA[n] = __builtin_amdgcn_mfma_f32_16x16x32_bf16(pfA1, vf[2 * n + 1], OA[n], 0, 0, 0);
        }
#pragma unroll
        for (int n = 0; n < 4; n++) {
            OB[n] = __builtin_amdgcn_mfma_f32_16x16x32_bf16(pfB0, vf[2 * n], OB[n], 0, 0, 0);
            OB[n] = __builtin_amdgcn_mfma_f32_16x16x32_bf16(pfB1, vf[2 * n + 1], OB[n], 0, 0, 0);
        }
        __builtin_amdgcn_s_setprio(0);
#pragma unroll
        for (int i = 0; i < 8; i++) kc[i] = kn[i];
    }

    const float fin = 0.03608439182435161f; // 1/sqrt(768), applied post-softmax
#pragma unroll
    for (int r = 0; r < 4; r++) {
        float linvA = fin / __shfl(lA, 4 * g + r);
        float linvB = fin / __shfl(lB, 4 * g + r);
        int rowA = b * SEQ_ + qbase + 4 * g + r;
        int rowB = rowA + 16;
        ushort* aoA = AO + (size_t)rowA * DIM_ + h * DH_ + lr;
        ushort* aoB = AO + (size_t)rowB * DIM_ + h * DH_ + lr;
#pragma unroll
        for (int n = 0; n < 4; n++) {
            aoA[n * 16] = f2bf(OA[n][r] * linvA);
            aoB[n * 16] = f2bf(OB[n][r] * linvB);
        }
    }
}

// ---------------- fused residual + LayerNorm (wave per row, float4) ----------------
__global__ __launch_bounds__(256) void ln_residual_kernel(
    const float* __restrict__ xin, const float* __restrict__ y,
    const float* __restrict__ g, const float* __restrict__ be,
    float* __restrict__ outf, ushort* __restrict__ outbf, int rows)
{
    int w = threadIdx.x >> 6, lane = threadIdx.x & 63;
    int row = blockIdx.x * 4 + w;
    if (row >= rows) return;
    const float4* yr = (const float4*)(y + (size_t)row * DIM_);
    float4 v[3];
    float s = 0.f, s2 = 0.f;
#pragma unroll
    for (int i = 0; i < 3; i++) {
        v[i] = yr[i * 64 + lane];
        s += (v[i].x + v[i].y) + (v[i].z + v[i].w);
        s2 += (v[i].x * v[i].x + v[i].y * v[i].y) + (v[i].z * v[i].z + v[i].w * v[i].w);
    }
#pragma unroll
    for (int o = 1; o < 64; o <<= 1) { s += __shfl_xor(s, o); s2 += __shfl_xor(s2, o); }
    float mu = s * (1.f / 768.f);
    float var = s2 * (1.f / 768.f) - mu * mu;
    float rs = rsqrtf(var + 1e-5f);
    const float4* xr = (const float4*)(xin + (size_t)row * DIM_);
    const float4* g4 = (const float4*)g;
    const float4* b4 = (const float4*)be;
    float4* of = (float4*)(outf + (size_t)row * DIM_);
#pragma unroll
    for (int i = 0; i < 3; i++) {
        int c = i * 64 + lane;
        float4 gg = g4[c], bb = b4[c], xx = xr[c];
        float4 o;
        o.x = xx.x + (v[i].x - mu) * rs * gg.x + bb.x;
        o.y = xx.y + (v[i].y - mu) * rs * gg.y + bb.y;
        o.z = xx.z + (v[i].z - mu) * rs * gg.z + bb.z;
        o.w = xx.w + (v[i].w - mu) * rs * gg.w + bb.w;
        of[c] = o;
        if (outbf) {
            ushort4 ob;
            ob.x = f2bf(o.x); ob.y = f2bf(o.y); ob.z = f2bf(o.z); ob.w = f2bf(o.w);
            ((ushort4*)(outbf + (size_t)row * DIM_))[c] = ob;
        }
    }
}

// ---------------- launch ----------------
extern "C" void kernel_launch(void* const* d_in, const int* in_sizes, int n_in,
                              void* d_out, int out_size, void* d_ws, size_t ws_size,
                              hipStream_t stream)
{
    const float* x    = (const float*)d_in[0];
    const float* Wqkv = (const float*)d_in[1];
    const float* bqkv = (const float*)d_in[2];
    const float* Wproj= (const float*)d_in[3];
    const float* bproj= (const float*)d_in[4];
    const float* W1   = (const float*)d_in[5];
    const float* b1   = (const float*)d_in[6];
    const float* W2   = (const float*)d_in[7];
    const float* b2   = (const float*)d_in[8];
    const float* g1   = (const float*)d_in[9];
    const float* be1  = (const float*)d_in[10];
    const float* g2   = (const float*)d_in[11];
    const float* be2  = (const float*)d_in[12];
    float* out = (float*)d_out;

    char* ws = (char*)d_ws;
    size_t off = 0;
    auto alloc = [&](size_t bytes) -> void* {
        void* p = ws + off;
        off += (bytes + 255) & ~(size_t)255;
        return p;
    };
    ushort* xbf    = (ushort*)alloc((size_t)ROWS_ * DIM_ * 2);
    ushort* wqkvT  = (ushort*)alloc((size_t)2304 * 768 * 2);
    ushort* wprojT = (ushort*)alloc((size_t)768 * 768 * 2);
    ushort* w1T    = (ushort*)alloc((size_t)3072 * 768 * 2);
    ushort* w2T    = (ushort*)alloc((size_t)768 * 3072 * 2);
    ushort* qb     = (ushort*)alloc((size_t)ROWS_ * DIM_ * 2);
    ushort* kb     = (ushort*)alloc((size_t)ROWS_ * DIM_ * 2);
    ushort* vT     = (ushort*)alloc((size_t)ROWS_ * DIM_ * 2);
    ushort* aobf   = (ushort*)alloc((size_t)ROWS_ * DIM_ * 2);
    float*  projf  = (float*) alloc((size_t)ROWS_ * DIM_ * 4);  // reused for mlp_out
    float*  x1f    = (float*) alloc((size_t)ROWS_ * DIM_ * 4);
    ushort* x1bf   = (ushort*)alloc((size_t)ROWS_ * DIM_ * 2);
    ushort* hbf    = (ushort*)alloc((size_t)ROWS_ * HID_ * 2);

    // prep
    cast_bf16_kernel<<<(ROWS_ * DIM_ / 4 + 255) / 256, 256, 0, stream>>>(x, xbf, ROWS_ * DIM_ / 4);
    transpose_cast_kernel<<<dim3(2304 / 32, 768 / 32), dim3(32, 8), 0, stream>>>(Wqkv, wqkvT, 768, 2304);
    transpose_cast_kernel<<<dim3(768 / 32, 768 / 32), dim3(32, 8), 0, stream>>>(Wproj, wprojT, 768, 768);
    transpose_cast_kernel<<<dim3(3072 / 32, 768 / 32), dim3(32, 8), 0, stream>>>(W1, w1T, 768, 3072);
    transpose_cast_kernel<<<dim3(768 / 32, 3072 / 32), dim3(32, 8), 0, stream>>>(W2, w2T, 3072, 768);

    // qkv = x @ Wqkv + bqkv  -> scatter into q/k/vT   (1152 blocks, nx=18)
    gemm_bt<EPI_QKV><<<1152, 256, 0, stream>>>(
        xbf, wqkvT, bqkv, nullptr, nullptr, qb, kb, vT, ROWS_, 2304, 768, 18);

    // attention -> aobf [8192][768]   (768 blocks, XCD-local heads)
    attn_kernel<<<768, 256, 0, stream>>>(qb, kb, vT, aobf);

    // proj   (384 blocks, nx=6)
    gemm_bt<EPI_F32><<<384, 256, 0, stream>>>(
        aobf, wprojT, bproj, projf, nullptr, nullptr, nullptr, nullptr, ROWS_, 768, 768, 6);

    // x1 = x + LN(proj)
    ln_residual_kernel<<<ROWS_ / 4, 256, 0, stream>>>(x, projf, g1, be1, x1f, x1bf, ROWS_);

    // h = gelu(x1 @ W1 + b1)   (1536 blocks, nx=24)
    gemm_bt<EPI_GELU><<<1536, 256, 0, stream>>>(
        x1bf, w1T, b1, nullptr, hbf, nullptr, nullptr, nullptr, ROWS_, 3072, 768, 24);

    // mlp = h @ W2 + b2 (reuse projf)   (384 blocks, nx=6)
    gemm_bt<EPI_F32><<<384, 256, 0, stream>>>(
        hbf, w2T, b2, projf, nullptr, nullptr, nullptr, nullptr, ROWS_, 768, 3072, 6);

    // out = x1 + LN(mlp)
    ln_residual_kernel<<<ROWS_ / 4, 256, 0, stream>>>(x1f, projf, g2, be2, out, nullptr, ROWS_);
}

// Round 7
// 312.933 us; speedup vs baseline: 1.4617x; 1.1448x over previous
//
#include <hip/hip_runtime.h>
#include <math.h>

typedef float f32x4 __attribute__((ext_vector_type(4)));
typedef short s16x8 __attribute__((ext_vector_type(8)));

#define DIM_ 768
#define HEADS_ 12
#define DH_ 64
#define HID_ 3072
#define SEQ_ 1024
#define BATCH_ 8
#define ROWS_ (BATCH_*SEQ_)   // 8192

static __device__ __forceinline__ ushort f2bf(float f) {
    union { float f; unsigned u; } v; v.f = f;
    unsigned r = (v.u + 0x7fffu + ((v.u >> 16) & 1u)) >> 16;
    return (ushort)r;
}

static __device__ __forceinline__ void glds16(const ushort* gp, ushort* lp) {
    __builtin_amdgcn_global_load_lds(
        (const __attribute__((address_space(1))) void*)gp,
        (__attribute__((address_space(3))) void*)lp, 16, 0, 0);
}

// ---------------- prep: cast x to bf16 ----------------
__global__ __launch_bounds__(256) void cast_bf16_kernel(
    const float* __restrict__ in, ushort* __restrict__ out, int n4)
{
    int i = blockIdx.x * 256 + threadIdx.x;
    if (i >= n4) return;
    float4 v = ((const float4*)in)[i];
    ushort4 o;
    o.x = f2bf(v.x); o.y = f2bf(v.y); o.z = f2bf(v.z); o.w = f2bf(v.w);
    ((ushort4*)out)[i] = o;
}

// ---------------- prep: transpose+cast W[K][N] -> WT[N][K] bf16 ----------------
__global__ __launch_bounds__(256) void transpose_cast_kernel(
    const float* __restrict__ W, ushort* __restrict__ WT, int K, int N)
{
    __shared__ float tile[32][33];
    int n0 = blockIdx.x * 32, k0 = blockIdx.y * 32;
    int tx = threadIdx.x, ty = threadIdx.y; // 32 x 8
#pragma unroll
    for (int i = 0; i < 4; i++)
        tile[ty + i * 8][tx] = W[(size_t)(k0 + ty + i * 8) * N + n0 + tx];
    __syncthreads();
#pragma unroll
    for (int i = 0; i < 4; i++)
        WT[(size_t)(n0 + ty + i * 8) * K + k0 + tx] = f2bf(tile[tx][ty + i * 8]);
}

// ---------------- GEMM: C = A @ BT^T + bias ----------------
// 128x128 tile, BK=64, XCD-chunked 1D grid, optional split-K (partials summed
// in the following LN kernel). LDS slot-swizzle per rule 21: linear glds16
// dest + XOR-pre-swizzled global SOURCE slot + same-XOR ds_read slot.
#define EPI_F32 0
#define EPI_GELU 1
#define EPI_QKV 2

template<int EPI>
__global__ __launch_bounds__(256, 2) void gemm_bt(
    const ushort* __restrict__ A, const ushort* __restrict__ B,
    const float* __restrict__ bias,
    float* __restrict__ Cf, ushort* __restrict__ Cbf,
    ushort* __restrict__ Qb, ushort* __restrict__ Kb, ushort* __restrict__ Vt,
    int M, int N, int K, int nx, int nk, int Ksl)
{
    __shared__ ushort As[128 * 64];
    __shared__ ushort Bs[128 * 64];
    const int t = threadIdx.x;
    const int lane = t & 63;
    const int w = t >> 6;
    const int wr = w >> 1, wc = w & 1;
    const int nwg = gridDim.x;
    const int chunk = nwg >> 3;
    const int lin = (blockIdx.x & 7) * chunk + (blockIdx.x >> 3);
    const int tile = lin / nk;
    const int ks = lin - tile * nk;
    const int m0 = (tile / nx) * 128, n0 = (tile % nx) * 128;
    const int lr = lane & 15, g = lane >> 4;

    const ushort* Ak = A + (size_t)ks * Ksl;
    const ushort* Bk = B + (size_t)ks * Ksl;
    // staging: lane -> row sr=lane>>3, dest 16B-slot lane&7; source slot
    // pre-swizzled ((lane&7)^sr) so read-side XOR recovers linear data.
    const int sr = lane >> 3;
    const int scz = (((lane & 7) ^ sr)) * 8;

    f32x4 acc[4][4] = {};

    for (int k0 = 0; k0 < Ksl; k0 += 64) {
#pragma unroll
        for (int j = 0; j < 4; j++) {
            int r = w * 32 + j * 8;
            glds16(Ak + (size_t)(m0 + r + sr) * K + k0 + scz, &As[r * 64]);
            glds16(Bk + (size_t)(n0 + r + sr) * K + k0 + scz, &Bs[r * 64]);
        }
        __syncthreads();
#pragma unroll
        for (int kk = 0; kk < 2; kk++) {
            s16x8 af[4], bfr[4];
#pragma unroll
            for (int m = 0; m < 4; m++) {
                int row = wr * 64 + m * 16 + lr;
                int slot = (kk * 4 + g) ^ (row & 7);
                af[m] = *(const s16x8*)&As[row * 64 + slot * 8];
            }
#pragma unroll
            for (int n = 0; n < 4; n++) {
                int row = wc * 64 + n * 16 + lr;
                int slot = (kk * 4 + g) ^ (row & 7);
                bfr[n] = *(const s16x8*)&Bs[row * 64 + slot * 8];
            }
#pragma unroll
            for (int m = 0; m < 4; m++)
#pragma unroll
                for (int n = 0; n < 4; n++)
                    acc[m][n] = __builtin_amdgcn_mfma_f32_16x16x32_bf16(af[m], bfr[n], acc[m][n], 0, 0, 0);
        }
        __syncthreads();
    }

    float* Cfo = Cf ? Cf + (size_t)ks * M * N : nullptr;
#pragma unroll
    for (int m = 0; m < 4; m++) {
        int row = m0 + wr * 64 + m * 16 + g * 4;
#pragma unroll
        for (int n = 0; n < 4; n++) {
            int col = n0 + wc * 64 + n * 16 + lr;
            float bv = (ks == 0) ? bias[col] : 0.f;
#pragma unroll
            for (int r = 0; r < 4; r++) {
                float v = acc[m][n][r] + bv;
                int rg = row + r;
                if (EPI == EPI_F32) {
                    Cfo[(size_t)rg * N + col] = v;
                } else if (EPI == EPI_GELU) {
                    float gl = 0.5f * v * (1.0f + erff(v * 0.70710678118654752f));
                    Cbf[(size_t)rg * N + col] = f2bf(gl);
                } else { // QKV scatter: col = h*192 + dh*3 + which
                    int b = rg >> 10, nrow = rg & 1023;
                    int h = col / 192, rem = col % 192;
                    int dh = rem / 3, wh = rem % 3;
                    int hb = b * HEADS_ + h;
                    ushort bw = f2bf(v);
                    if (wh == 0)      Qb[((size_t)hb * SEQ_ + nrow) * DH_ + dh] = bw;
                    else if (wh == 1) Kb[((size_t)hb * SEQ_ + nrow) * DH_ + dh] = bw;
                    else              Vt[(size_t)hb * DH_ * SEQ_ + (size_t)dh * SEQ_ + nrow] = bw;
                }
            }
        }
    }
}

// ---- softmax + pack + permlane redistribution (R5-validated version) ----
static __device__ __forceinline__ void softmax_pack(
    f32x4 (&S)[4], float& mrow, float& lrow, float& scale,
    s16x8& pf0v, s16x8& pf1v)
{
    f32x4 mm = S[0];
#pragma unroll
    for (int n = 1; n < 4; n++) {
#pragma unroll
        for (int r = 0; r < 4; r++) mm[r] = fmaxf(mm[r], S[n][r]);
    }
    float mx = fmaxf(fmaxf(mm[0], mm[1]), fmaxf(mm[2], mm[3]));
    mx = fmaxf(mx, __shfl_xor(mx, 16));
    mx = fmaxf(mx, __shfl_xor(mx, 32));
    float mn = fmaxf(mrow, mx);
    scale = __expf(mrow - mn);
    mrow = mn;
#pragma unroll
    for (int n = 0; n < 4; n++)
#pragma unroll
        for (int r = 0; r < 4; r++) S[n][r] = __expf(S[n][r] - mn);
    f32x4 ssv = S[0];
#pragma unroll
    for (int n = 1; n < 4; n++) ssv += S[n];
    float ssum = (ssv[0] + ssv[1]) + (ssv[2] + ssv[3]);
    ssum += __shfl_xor(ssum, 16);
    ssum += __shfl_xor(ssum, 32);
    lrow = lrow * scale + ssum;

    unsigned c[4][2];
#pragma unroll
    for (int n = 0; n < 4; n++) {
        asm("v_cvt_pk_bf16_f32 %0, %1, %2" : "=v"(c[n][0]) : "v"(S[n][0]), "v"(S[n][1]));
        asm("v_cvt_pk_bf16_f32 %0, %1, %2" : "=v"(c[n][1]) : "v"(S[n][2]), "v"(S[n][3]));
    }
    union { unsigned u[4]; s16x8 v; } pf0, pf1;
#pragma unroll
    for (int m = 0; m < 2; m++) {
        unsigned a = c[0][m], bb = c[1][m];
        asm("v_permlane32_swap_b32 %0, %1" : "+v"(a), "+v"(bb));
        asm("v_permlane16_swap_b32 %0, %1" : "+v"(a), "+v"(bb));
        pf0.u[m] = a; pf0.u[2 + m] = bb;
        unsigned a2 = c[2][m], b2 = c[3][m];
        asm("v_permlane32_swap_b32 %0, %1" : "+v"(a2), "+v"(b2));
        asm("v_permlane16_swap_b32 %0, %1" : "+v"(a2), "+v"(b2));
        pf1.u[m] = a2; pf1.u[2 + m] = b2;
    }
    pf0v = pf0.v; pf1v = pf1.v;
}

// ---------------- flash attention (R5-validated): 32 q/wave, K reg-prefetch,
// XCD-local heads ----------------
__global__ __launch_bounds__(256) void attn_kernel(
    const ushort* __restrict__ Q, const ushort* __restrict__ Kb,
    const ushort* __restrict__ Vt, ushort* __restrict__ AO)
{
    const int t = threadIdx.x, lane = t & 63, w = t >> 6;
    const int lr = lane & 15, g = lane >> 4;
    const int wg = blockIdx.x;                 // 0..767
    const int lin = (wg & 7) * 96 + (wg >> 3); // XCD-contiguous work id
    const int bh = lin >> 3;                   // 12 heads per XCD
    const int qt = lin & 7;
    const int b = bh / HEADS_, h = bh % HEADS_;
    const ushort* qh = Q + (size_t)bh * SEQ_ * DH_;
    const ushort* kh = Kb + (size_t)bh * SEQ_ * DH_;
    const ushort* vh = Vt + (size_t)bh * DH_ * SEQ_;

    const int qbase = qt * 128 + w * 32;
    s16x8 aqA0 = *(const s16x8*)(qh + (size_t)(qbase + lr) * DH_ + g * 8);
    s16x8 aqA1 = *(const s16x8*)(qh + (size_t)(qbase + lr) * DH_ + 32 + g * 8);
    s16x8 aqB0 = *(const s16x8*)(qh + (size_t)(qbase + 16 + lr) * DH_ + g * 8);
    s16x8 aqB1 = *(const s16x8*)(qh + (size_t)(qbase + 16 + lr) * DH_ + 32 + g * 8);

    float mA = -INFINITY, lA = 0.f, mB = -INFINITY, lB = 0.f;
    f32x4 OA[4] = {}, OB[4] = {};

    s16x8 kc[8], kn[8];
#pragma unroll
    for (int n = 0; n < 4; n++) {
        const ushort* kp = kh + (size_t)(n * 16 + lr) * DH_ + g * 8;
        kc[2 * n]     = *(const s16x8*)kp;
        kc[2 * n + 1] = *(const s16x8*)(kp + 32);
    }

    for (int tkv = 0; tkv < 16; ++tkv) {
        const int kbase = tkv * 64;
        if (tkv < 15) {
#pragma unroll
            for (int n = 0; n < 4; n++) {
                const ushort* kp = kh + (size_t)(kbase + 64 + n * 16 + lr) * DH_ + g * 8;
                kn[2 * n]     = *(const s16x8*)kp;
                kn[2 * n + 1] = *(const s16x8*)(kp + 32);
            }
        }
        f32x4 SA[4] = {};
#pragma unroll
        for (int n = 0; n < 4; n++) {
            SA[n] = __builtin_amdgcn_mfma_f32_16x16x32_bf16(kc[2 * n], aqA0, SA[n], 0, 0, 0);
            SA[n] = __builtin_amdgcn_mfma_f32_16x16x32_bf16(kc[2 * n + 1], aqA1, SA[n], 0, 0, 0);
        }
        s16x8 vf[8];
#pragma unroll
        for (int n = 0; n < 4; n++) {
            const ushort* vp = vh + (size_t)(n * 16 + lr) * SEQ_ + kbase + g * 8;
            vf[2 * n]     = *(const s16x8*)vp;
            vf[2 * n + 1] = *(const s16x8*)(vp + 32);
        }
        f32x4 SB[4] = {};
#pragma unroll
        for (int n = 0; n < 4; n++) {
            SB[n] = __builtin_amdgcn_mfma_f32_16x16x32_bf16(kc[2 * n], aqB0, SB[n], 0, 0, 0);
            SB[n] = __builtin_amdgcn_mfma_f32_16x16x32_bf16(kc[2 * n + 1], aqB1, SB[n], 0, 0, 0);
        }
        float scA, scB;
        s16x8 pfA0, pfA1, pfB0, pfB1;
        softmax_pack(SA, mA, lA, scA, pfA0, pfA1);
        softmax_pack(SB, mB, lB, scB, pfB0, pfB1);
        float a0 = __shfl(scA, 4 * g + 0), a1 = __shfl(scA, 4 * g + 1);
        float a2 = __shfl(scA, 4 * g + 2), a3 = __shfl(scA, 4 * g + 3);
        float b0 = __shfl(scB, 4 * g + 0), b1 = __shfl(scB, 4 * g + 1);
        float b2 = __shfl(scB, 4 * g + 2), b3 = __shfl(scB, 4 * g + 3);
#pragma unroll
        for (int n = 0; n < 4; n++) {
            OA[n][0] *= a0; OA[n][1] *= a1; OA[n][2] *= a2; OA[n][3] *= a3;
            OB[n][0] *= b0; OB[n][1] *= b1; OB[n][2] *= b2; OB[n][3] *= b3;
        }
        __builtin_amdgcn_s_setprio(1);
#pragma unroll
        for (int n = 0; n < 4; n++) {
            OA[n] = __builtin_amdgcn_mfma_f32_16x16x32_bf16(pfA0, vf[2 * n], OA[n], 0, 0, 0);
            OA[n] = __builtin_amdgcn_mfma_f32_16x16x32_bf16(pfA1, vf[2 * n + 1], OA[n], 0, 0, 0);
        }
#pragma unroll
        for (int n = 0; n < 4; n++) {
            OB[n] = __builtin_amdgcn_mfma_f32_16x16x32_bf16(pfB0, vf[2 * n], OB[n], 0, 0, 0);
            OB[n] = __builtin_amdgcn_mfma_f32_16x16x32_bf16(pfB1, vf[2 * n + 1], OB[n], 0, 0, 0);
        }
        __builtin_amdgcn_s_setprio(0);
#pragma unroll
        for (int i = 0; i < 8; i++) kc[i] = kn[i];
    }

    const float fin = 0.03608439182435161f; // 1/sqrt(768), applied post-softmax
#pragma unroll
    for (int r = 0; r < 4; r++) {
        float linvA = fin / __shfl(lA, 4 * g + r);
        float linvB = fin / __shfl(lB, 4 * g + r);
        int rowA = b * SEQ_ + qbase + 4 * g + r;
        int rowB = rowA + 16;
        ushort* aoA = AO + (size_t)rowA * DIM_ + h * DH_ + lr;
        ushort* aoB = AO + (size_t)rowB * DIM_ + h * DH_ + lr;
#pragma unroll
        for (int n = 0; n < 4; n++) {
            aoA[n * 16] = f2bf(OA[n][r] * linvA);
            aoB[n * 16] = f2bf(OB[n][r] * linvB);
        }
    }
}

// ---------------- fused residual + LayerNorm (wave per row, float4) ----------------
// y = y0 (+ y1 if non-null): sums split-K partials for free.
__global__ __launch_bounds__(256) void ln_residual_kernel(
    const float* __restrict__ xin, const float* __restrict__ y0,
    const float* __restrict__ y1,
    const float* __restrict__ g, const float* __restrict__ be,
    float* __restrict__ outf, ushort* __restrict__ outbf, int rows)
{
    int w = threadIdx.x >> 6, lane = threadIdx.x & 63;
    int row = blockIdx.x * 4 + w;
    if (row >= rows) return;
    const float4* y0r = (const float4*)(y0 + (size_t)row * DIM_);
    const float4* y1r = y1 ? (const float4*)(y1 + (size_t)row * DIM_) : nullptr;
    float4 v[3];
    float s = 0.f, s2 = 0.f;
#pragma unroll
    for (int i = 0; i < 3; i++) {
        float4 a = y0r[i * 64 + lane];
        if (y1r) {
            float4 bb = y1r[i * 64 + lane];
            a.x += bb.x; a.y += bb.y; a.z += bb.z; a.w += bb.w;
        }
        v[i] = a;
        s += (a.x + a.y) + (a.z + a.w);
        s2 += (a.x * a.x + a.y * a.y) + (a.z * a.z + a.w * a.w);
    }
#pragma unroll
    for (int o = 1; o < 64; o <<= 1) { s += __shfl_xor(s, o); s2 += __shfl_xor(s2, o); }
    float mu = s * (1.f / 768.f);
    float var = s2 * (1.f / 768.f) - mu * mu;
    float rs = rsqrtf(var + 1e-5f);
    const float4* xr = (const float4*)(xin + (size_t)row * DIM_);
    const float4* g4 = (const float4*)g;
    const float4* b4 = (const float4*)be;
    float4* of = (float4*)(outf + (size_t)row * DIM_);
#pragma unroll
    for (int i = 0; i < 3; i++) {
        int c = i * 64 + lane;
        float4 gg = g4[c], bb = b4[c], xx = xr[c];
        float4 o;
        o.x = xx.x + (v[i].x - mu) * rs * gg.x + bb.x;
        o.y = xx.y + (v[i].y - mu) * rs * gg.y + bb.y;
        o.z = xx.z + (v[i].z - mu) * rs * gg.z + bb.z;
        o.w = xx.w + (v[i].w - mu) * rs * gg.w + bb.w;
        of[c] = o;
        if (outbf) {
            ushort4 ob;
            ob.x = f2bf(o.x); ob.y = f2bf(o.y); ob.z = f2bf(o.z); ob.w = f2bf(o.w);
            ((ushort4*)(outbf + (size_t)row * DIM_))[c] = ob;
        }
    }
}

// ---------------- launch ----------------
extern "C" void kernel_launch(void* const* d_in, const int* in_sizes, int n_in,
                              void* d_out, int out_size, void* d_ws, size_t ws_size,
                              hipStream_t stream)
{
    const float* x    = (const float*)d_in[0];
    const float* Wqkv = (const float*)d_in[1];
    const float* bqkv = (const float*)d_in[2];
    const float* Wproj= (const float*)d_in[3];
    const float* bproj= (const float*)d_in[4];
    const float* W1   = (const float*)d_in[5];
    const float* b1   = (const float*)d_in[6];
    const float* W2   = (const float*)d_in[7];
    const float* b2   = (const float*)d_in[8];
    const float* g1   = (const float*)d_in[9];
    const float* be1  = (const float*)d_in[10];
    const float* g2   = (const float*)d_in[11];
    const float* be2  = (const float*)d_in[12];
    float* out = (float*)d_out;

    char* ws = (char*)d_ws;
    size_t off = 0;
    auto alloc = [&](size_t bytes) -> void* {
        void* p = ws + off;
        off += (bytes + 255) & ~(size_t)255;
        return p;
    };
    // weights first (live all along)
    ushort* wqkvT  = (ushort*)alloc((size_t)2304 * 768 * 2);
    ushort* wprojT = (ushort*)alloc((size_t)768 * 768 * 2);
    ushort* w1T    = (ushort*)alloc((size_t)3072 * 768 * 2);
    ushort* w2T    = (ushort*)alloc((size_t)768 * 3072 * 2);
    // BLOCK_A: xbf/qb/kb/vT (dead after attn) — exactly 50,331,648 B,
    // aliased by hbf (written by W1 GEMM, after attn).
    ushort* xbf    = (ushort*)alloc((size_t)ROWS_ * DIM_ * 2);
    ushort* qb     = (ushort*)alloc((size_t)ROWS_ * DIM_ * 2);
    ushort* kb     = (ushort*)alloc((size_t)ROWS_ * DIM_ * 2);
    ushort* vT     = (ushort*)alloc((size_t)ROWS_ * DIM_ * 2);
    ushort* hbf    = xbf;  // alias: 4*ROWS*DIM*2 == ROWS*HID*2
    ushort* aobf   = (ushort*)alloc((size_t)ROWS_ * DIM_ * 2);
    float*  projp  = (float*) alloc((size_t)2 * ROWS_ * DIM_ * 4); // split-K partials
    float*  x1f    = (float*) alloc((size_t)ROWS_ * DIM_ * 4);
    ushort* x1bf   = (ushort*)alloc((size_t)ROWS_ * DIM_ * 2);
    float*  projp1 = projp + (size_t)ROWS_ * DIM_;

    // prep
    cast_bf16_kernel<<<(ROWS_ * DIM_ / 4 + 255) / 256, 256, 0, stream>>>(x, xbf, ROWS_ * DIM_ / 4);
    transpose_cast_kernel<<<dim3(2304 / 32, 768 / 32), dim3(32, 8), 0, stream>>>(Wqkv, wqkvT, 768, 2304);
    transpose_cast_kernel<<<dim3(768 / 32, 768 / 32), dim3(32, 8), 0, stream>>>(Wproj, wprojT, 768, 768);
    transpose_cast_kernel<<<dim3(3072 / 32, 768 / 32), dim3(32, 8), 0, stream>>>(W1, w1T, 768, 3072);
    transpose_cast_kernel<<<dim3(768 / 32, 3072 / 32), dim3(32, 8), 0, stream>>>(W2, w2T, 3072, 768);

    // qkv = x @ Wqkv + bqkv -> scatter into q/k/vT  (1152 blocks, nx=18)
    gemm_bt<EPI_QKV><<<1152, 256, 0, stream>>>(
        xbf, wqkvT, bqkv, nullptr, nullptr, qb, kb, vT, ROWS_, 2304, 768, 18, 1, 768);

    // attention -> aobf (768 blocks, XCD-local heads)
    attn_kernel<<<768, 256, 0, stream>>>(qb, kb, vT, aobf);

    // proj: split-K x2 (768 blocks, nx=6, Ksl=384) -> projp0, projp1
    gemm_bt<EPI_F32><<<768, 256, 0, stream>>>(
        aobf, wprojT, bproj, projp, nullptr, nullptr, nullptr, nullptr, ROWS_, 768, 768, 6, 2, 384);

    // x1 = x + LN(projp0 + projp1)
    ln_residual_kernel<<<ROWS_ / 4, 256, 0, stream>>>(x, projp, projp1, g1, be1, x1f, x1bf, ROWS_);

    // h = gelu(x1 @ W1 + b1)  (1536 blocks, nx=24) — hbf aliases dead BLOCK_A
    gemm_bt<EPI_GELU><<<1536, 256, 0, stream>>>(
        x1bf, w1T, b1, nullptr, hbf, nullptr, nullptr, nullptr, ROWS_, 3072, 768, 24, 1, 768);

    // mlp = h @ W2 + b2: split-K x2 (768 blocks, nx=6, Ksl=1536) -> projp0, projp1
    gemm_bt<EPI_F32><<<768, 256, 0, stream>>>(
        hbf, w2T, b2, projp, nullptr, nullptr, nullptr, nullptr, ROWS_, 768, 3072, 6, 2, 1536);

    // out = x1 + LN(mlp0 + mlp1)
    ln_residual_kernel<<<ROWS_ / 4, 256, 0, stream>>>(x1f, projp, projp1, g2, be2, out, nullptr, ROWS_);
}